// Round 16
// baseline (299.819 us; speedup 1.0000x reference)
//
#include <hip/hip_runtime.h>
#include <hip/hip_bf16.h>
#include <cstdint>

// ---------------- problem constants ----------------
namespace {
constexpr int BB = 4;
constexpr int CC = 27;
constexpr int HW = 448 * 448;                 // 200704
constexpr long long CHW = (long long)CC * HW; // 5419008
constexpr int NP = 196;                        // patch positions
constexpr int GG = 56 * 56;                    // 3136 pooled positions
constexpr int DTOT = CC * 1024;                // 27648
constexpr float SCALE_P = 0.0060140449f;       // 1/sqrt(27648)
constexpr float SCALE_G = 0.1924500897f;       // 1/sqrt(27)
constexpr float EPSV = 1e-5f;
// MFMA spart config
constexpr int KCH = 512;                       // d-chunk per block
constexpr int NKS = DTOT / KCH;                // 54 partials
constexpr int MPAD = 224;                      // padded n/m (14 tiles of 16)
constexpr int ROWB = 128;                      // LDS bytes per row
// wHat fragment-major, step-major: [7 step][13 ct][64 lane][8 elem] bf16 = 46592 elems
constexpr int WFRAG = 7 * 13 * 64 * 8;
// qkv-MFMA config
constexpr int XST = 40;                        // LDS row stride (shorts)
// flash gattn config
constexpr int GKC = 224;                       // keys per chunk (14 chunks)
constexpr int KST = 40;                        // ks row stride (shorts)
constexpr int VST = 232;                       // vs/ps row stride (shorts)
// hp epilogue LDS stride (shorts, bf16); 32 rows -> 13056 B
constexpr int HST = 204;
}

typedef __attribute__((ext_vector_type(8))) short short8;
typedef __attribute__((ext_vector_type(4))) float f32x4;

__device__ __forceinline__ float bf2f(unsigned short u) {
    return __uint_as_float(((uint32_t)u) << 16);
}

__device__ __forceinline__ ushort f2bf(float f) {
    union { __hip_bfloat16 h; ushort u; } cv;
    cv.h = __float2bfloat16(f);
    return cv.u;
}

// ---------------- 0. fold proj into V weights: pvw = proj*vw, pvb = proj*vb ----------------
__global__ void k_fold(const float* __restrict__ pjw, const float* __restrict__ vw,
                       const float* __restrict__ vb, float* __restrict__ pvw,
                       float* __restrict__ pvb) {
    __shared__ float pj[729], vv[729], vbs[27];
    int t = threadIdx.x;
    for (int i = t; i < 729; i += 256) { pj[i] = pjw[i]; vv[i] = vw[i]; }
    if (t < 27) vbs[t] = vb[t];
    __syncthreads();
    for (int i = t; i < 729; i += 256) {
        int o = i / 27, c2 = i - (i / 27) * 27;
        float s = 0.f;
#pragma unroll
        for (int c = 0; c < 27; c++) s += pj[o * 27 + c] * vv[c * 27 + c2];
        pvw[i] = s;
    }
    if (t < 27) {
        float s = 0.f;
#pragma unroll
        for (int c = 0; c < 27; c++) s += pj[t * 27 + c] * vbs[c];
        pvb[t] = s;
    }
}

// ---------------- 1. GroupNorm stats ----------------
__global__ void k_gn_partial(const float* __restrict__ x, float* __restrict__ part) {
    int blk = blockIdx.x;          // BB*1024 blocks
    int b = blk >> 10;
    int chunk = blk & 1023;
    const int CLEN = (int)(CHW / 1024);   // 5292
    const float* p = x + (size_t)b * CHW + (size_t)chunk * CLEN;
    float s = 0.f, ss = 0.f;
    for (int i = threadIdx.x; i < CLEN; i += 256) {
        float v = p[i];
        s += v; ss += v * v;
    }
    for (int o = 32; o; o >>= 1) { s += __shfl_down(s, o); ss += __shfl_down(ss, o); }
    __shared__ float ls[4], lss[4];
    int wid = threadIdx.x >> 6, lane = threadIdx.x & 63;
    if (lane == 0) { ls[wid] = s; lss[wid] = ss; }
    __syncthreads();
    if (threadIdx.x == 0) {
        float S = ls[0] + ls[1] + ls[2] + ls[3];
        float SS = lss[0] + lss[1] + lss[2] + lss[3];
        part[blk * 2] = S; part[blk * 2 + 1] = SS;
    }
}

__global__ void k_gn_final(const float* __restrict__ part, float* __restrict__ stats) {
    int b = blockIdx.x;
    float s = 0.f, ss = 0.f;
    for (int i = threadIdx.x; i < 1024; i += 256) {
        s += part[(b * 1024 + i) * 2];
        ss += part[(b * 1024 + i) * 2 + 1];
    }
    for (int o = 32; o; o >>= 1) { s += __shfl_down(s, o); ss += __shfl_down(ss, o); }
    __shared__ float ls[4], lss[4];
    int wid = threadIdx.x >> 6, lane = threadIdx.x & 63;
    if (lane == 0) { ls[wid] = s; lss[wid] = ss; }
    __syncthreads();
    if (threadIdx.x == 0) {
        float S = ls[0] + ls[1] + ls[2] + ls[3];
        float SS = lss[0] + lss[1] + lss[2] + lss[3];
        float mean = S / (float)CHW;
        float var = SS / (float)CHW - mean * mean;
        stats[b * 2] = mean;
        stats[b * 2 + 1] = rsqrtf(var + EPSV);
    }
}

// ---------------- 2. GN-apply + QKV conv1x1 via MFMA (-> bf16) ----------------
__global__ __launch_bounds__(256, 2)
void k_qkv_mfma(const float* __restrict__ x, const float* __restrict__ stats,
                const float* __restrict__ qw, const float* __restrict__ qb,
                const float* __restrict__ kw, const float* __restrict__ kb,
                const float* __restrict__ vw, const float* __restrict__ vb,
                const float* __restrict__ gnw, const float* __restrict__ gnb,
                __hip_bfloat16* __restrict__ qkv) {
    __shared__ ushort xs[256 * XST];            // 20480 B
    __shared__ ushort wls[96 * XST];            // 7680 B
    __shared__ __align__(16) float bls[96];
    __shared__ float gwls[27], gbls[27];

    int tid = threadIdx.x;
    int P0 = blockIdx.x * 256;                  // global pixel base
    int b = P0 / HW;                            // HW % 256 == 0: no straddle
    int hw0 = P0 - b * HW;

    for (int i = tid; i < 96 * 32; i += 256) {
        int row = i >> 5, c = i & 31;
        float wv = 0.f;
        if (c < 27 && row < 81) {
            int t = (row >= 54) ? 2 : (row >= 27 ? 1 : 0);
            int oc = row - t * 27;
            const float* wp = (t == 0) ? qw : (t == 1) ? kw : vw;
            wv = wp[oc * 27 + c];
        }
        wls[row * XST + c] = f2bf(wv);
    }
    if (tid < 96) {
        float bv = 0.f;
        if (tid < 27) bv = qb[tid];
        else if (tid < 54) bv = kb[tid - 27];
        else if (tid < 81) bv = vb[tid - 54];
        bls[tid] = bv;
    }
    if (tid < 27) { gwls[tid] = gnw[tid]; gbls[tid] = gnb[tid]; }
    float mean = stats[b * 2], rstd = stats[b * 2 + 1];
    __syncthreads();

    {
        const float* xp = x + (size_t)b * CHW + hw0 + tid;
        ushort xv[28];
#pragma unroll
        for (int c = 0; c < 27; c++) {
            float v = (xp[(size_t)c * HW] - mean) * rstd * gwls[c] + gbls[c];
            xv[c] = f2bf(v);
        }
        xv[27] = 0;
        uint32_t* xrow = reinterpret_cast<uint32_t*>(&xs[tid * XST]);
#pragma unroll
        for (int i = 0; i < 14; i++)
            xrow[i] = (uint32_t)xv[2 * i] | ((uint32_t)xv[2 * i + 1] << 16);
        xrow[14] = 0; xrow[15] = 0;
    }
    __syncthreads();

    int w = tid >> 6, l = tid & 63;
    int lrow = l & 15, kg = l >> 4;

    short8 afr[6];
    f32x4 binit[6];
#pragma unroll
    for (int mt = 0; mt < 6; mt++) {
        afr[mt] = *reinterpret_cast<const short8*>(&wls[(mt * 16 + lrow) * XST + kg * 8]);
        binit[mt] = *reinterpret_cast<const f32x4*>(&bls[mt * 16 + kg * 4]);
    }

    f32x4 acc[4][6];
#pragma unroll
    for (int pt = 0; pt < 4; pt++) {
        const short8 bfr = *reinterpret_cast<const short8*>(
            &xs[(w * 64 + pt * 16 + lrow) * XST + kg * 8]);
#pragma unroll
        for (int mt = 0; mt < 6; mt++)
            acc[pt][mt] = __builtin_amdgcn_mfma_f32_16x16x32_bf16(afr[mt], bfr, binit[mt], 0, 0, 0);
    }

    ushort* ob = (ushort*)qkv;
#pragma unroll
    for (int pt = 0; pt < 4; pt++) {
        int hw = hw0 + w * 64 + pt * 16 + lrow;
#pragma unroll
        for (int mt = 0; mt < 6; mt++) {
#pragma unroll
            for (int r = 0; r < 4; r++) {
                int o = mt * 16 + kg * 4 + r;
                if (o < 81) {
                    int t = (o >= 54) ? 2 : (o >= 27 ? 1 : 0);
                    int oc = o - t * 27;
                    ob[((size_t)t * BB + b) * CHW + (size_t)oc * HW + hw] = f2bf(acc[pt][mt][r]);
                }
            }
        }
    }
}

// ---------------- 3. 8x8 avg pool -> transposed [b][g][27] ----------------
__global__ void k_pool(const __hip_bfloat16* __restrict__ src, float* __restrict__ dst) {
    int idx = blockIdx.x * 256 + threadIdx.x;  // < 4*27*3136 = 338688
    int g = idx % GG;
    int t = idx / GG;
    int c = t % 27;
    int b = t / 27;
    int gh = g / 56, gw = g - (g / 56) * 56;
    const ushort* sp = (const ushort*)src + (size_t)(b * 27 + c) * HW + (size_t)(gh * 8) * 448 + gw * 8;
    float s = 0.f;
#pragma unroll
    for (int r = 0; r < 8; r++) {
        const ushort4 a = *reinterpret_cast<const ushort4*>(sp + r * 448);
        const ushort4 d = *reinterpret_cast<const ushort4*>(sp + r * 448 + 4);
        s += bf2f(a.x) + bf2f(a.y) + bf2f(a.z) + bf2f(a.w)
           + bf2f(d.x) + bf2f(d.y) + bf2f(d.z) + bf2f(d.w);
    }
    dst[((size_t)b * GG + g) * 27 + c] = s * (1.f / 64.f);
}

// ---------------- 4a. patch attention S partials via MFMA ----------------
__global__ __launch_bounds__(448, 1)
void k_spart_mfma(const __hip_bfloat16* __restrict__ q, const __hip_bfloat16* __restrict__ k,
                  float* __restrict__ spart) {
    __shared__ ushort lq[MPAD * 64];   // 28672 B
    __shared__ ushort lk[MPAD * 64];
    int blk = blockIdx.x;              // 4b * 54ks = 216
    int ks = blk % NKS;
    int b = blk / NKS;
    const ushort* qb_ = (const ushort*)q + (size_t)b * CHW;
    const ushort* kb_ = (const ushort*)k + (size_t)b * CHW;
    int t = threadIdx.x;
    int w = t >> 6, l = t & 63;
    int lrow = l & 15, lg = l >> 4;    // fragment coords
    int sr = t & 15;                   // d-pair index 0..15 (d = 2sr, 2sr+1)
    int sn8 = t >> 4;                  // col-chunk 0..27 (cols sn8*8..+8)

    f32x4 acc[2][13];
#pragma unroll
    for (int i = 0; i < 2; i++)
#pragma unroll
        for (int ct = 0; ct < 13; ct++) acc[i][ct] = (f32x4){0.f, 0.f, 0.f, 0.f};

    int d0 = ks * KCH;
    for (int step = 0; step < KCH / 32; ++step) {
        int dbase = d0 + step * 32;
        {
            const ushort* s0 = qb_ + (size_t)(dbase + 2 * sr) * NP + sn8 * 8;
            const ushort* s1 = s0 + NP;
            ushort4 a0 = *reinterpret_cast<const ushort4*>(s0);
            ushort4 a1 = *reinterpret_cast<const ushort4*>(s0 + 4);
            ushort4 b0 = *reinterpret_cast<const ushort4*>(s1);
            ushort4 b1 = *reinterpret_cast<const ushort4*>(s1 + 4);
            ushort ra[8] = {a0.x, a0.y, a0.z, a0.w, a1.x, a1.y, a1.z, a1.w};
            ushort rb[8] = {b0.x, b0.y, b0.z, b0.w, b1.x, b1.y, b1.z, b1.w};
#pragma unroll
            for (int kk = 0; kk < 8; kk++) {
                int n = sn8 * 8 + kk;
                uint32_t val = (uint32_t)ra[kk] | ((uint32_t)rb[kk] << 16);
                *reinterpret_cast<uint32_t*>(reinterpret_cast<char*>(lq) + n * ROWB +
                                             ((4 * sr) ^ (16 * (n & 7)))) = val;
            }
        }
        {
            const ushort* s0 = kb_ + (size_t)(dbase + 2 * sr) * NP + sn8 * 8;
            const ushort* s1 = s0 + NP;
            ushort4 a0 = *reinterpret_cast<const ushort4*>(s0);
            ushort4 a1 = *reinterpret_cast<const ushort4*>(s0 + 4);
            ushort4 b0 = *reinterpret_cast<const ushort4*>(s1);
            ushort4 b1 = *reinterpret_cast<const ushort4*>(s1 + 4);
            ushort ra[8] = {a0.x, a0.y, a0.z, a0.w, a1.x, a1.y, a1.z, a1.w};
            ushort rb[8] = {b0.x, b0.y, b0.z, b0.w, b1.x, b1.y, b1.z, b1.w};
#pragma unroll
            for (int kk = 0; kk < 8; kk++) {
                int m = sn8 * 8 + kk;
                uint32_t val = (uint32_t)ra[kk] | ((uint32_t)rb[kk] << 16);
                *reinterpret_cast<uint32_t*>(reinterpret_cast<char*>(lk) + m * ROWB +
                                             ((4 * sr) ^ (16 * (m & 7)))) = val;
            }
        }
        __syncthreads();
        int nA0 = (2 * w) * 16 + lrow;
        int nA1 = nA0 + 16;
        const short8 afr0 = *reinterpret_cast<const short8*>(
            reinterpret_cast<const char*>(lq) + nA0 * ROWB + 16 * (lg ^ (nA0 & 7)));
        const short8 afr1 = *reinterpret_cast<const short8*>(
            reinterpret_cast<const char*>(lq) + nA1 * ROWB + 16 * (lg ^ (nA1 & 7)));
#pragma unroll
        for (int ct = 0; ct < 13; ct++) {
            int m = ct * 16 + lrow;
            const short8 bfr = *reinterpret_cast<const short8*>(
                reinterpret_cast<const char*>(lk) + m * ROWB + 16 * (lg ^ (m & 7)));
            acc[0][ct] = __builtin_amdgcn_mfma_f32_16x16x32_bf16(afr0, bfr, acc[0][ct], 0, 0, 0);
            acc[1][ct] = __builtin_amdgcn_mfma_f32_16x16x32_bf16(afr1, bfr, acc[1][ct], 0, 0, 0);
        }
        __syncthreads();
    }
    float* sp = spart + (size_t)(b * NKS + ks) * NP * MPAD;
#pragma unroll
    for (int i = 0; i < 2; i++) {
        int rt = 2 * w + i;
#pragma unroll
        for (int r = 0; r < 4; r++) {
            int n = rt * 16 + lg * 4 + r;
            if (n < NP) {
#pragma unroll
                for (int ct = 0; ct < 13; ct++)
                    sp[(size_t)n * MPAD + ct * 16 + lrow] = acc[i][ct][r];
            }
        }
    }
}

// ---------------- 4b. reduce + row softmax -> whf fragment-major (step-major) bf16 ----------------
__global__ void k_softmax(const float* __restrict__ spart, __hip_bfloat16* __restrict__ whf) {
    int blk = blockIdx.x;        // BB*196
    int n = blk % NP;            // query row
    int b = blk / NP;
    int m = threadIdx.x;         // key col
    float val = -1e30f;
    if (m < 196) {
        float s = 0.f;
        for (int ks = 0; ks < NKS; ks++)
            s += spart[((size_t)(b * NKS + ks) * NP + n) * MPAD + m];
        val = s * SCALE_P;
    }
    float mx = val;
    for (int o = 32; o; o >>= 1) mx = fmaxf(mx, __shfl_xor(mx, o));
    __shared__ float redm[4], reds[4];
    int wid = threadIdx.x >> 6, lane = threadIdx.x & 63;
    if (lane == 0) redm[wid] = mx;
    __syncthreads();
    mx = fmaxf(fmaxf(redm[0], redm[1]), fmaxf(redm[2], redm[3]));
    float p = (m < 196) ? __expf(val - mx) : 0.f;
    float sm = p;
    for (int o = 32; o; o >>= 1) sm += __shfl_xor(sm, o);
    if (lane == 0) reds[wid] = sm;
    __syncthreads();
    sm = reds[0] + reds[1] + reds[2] + reds[3];
    if (m < 224) {
        int ct = n >> 4, lr = n & 15;
        int step = m >> 5, kg = (m >> 3) & 3, e = m & 7;
        size_t addr = (size_t)b * WFRAG +
                      (((size_t)(step * 13 + ct) * 64 + kg * 16 + lr) << 3) + e;
        whf[addr] = __float2bfloat16((m < 196) ? p / sm : 0.f);
    }
}

// ---------------- 5. global pooled attention: flash MFMA ----------------
__global__ __launch_bounds__(256)
void k_gattn_flash(const float* __restrict__ qg, const float* __restrict__ kg,
                   const float* __restrict__ vg, float* __restrict__ hg) {
    __shared__ __align__(16) ushort ksh[GKC * KST];    // [k][d] 17920 B
    __shared__ __align__(16) ushort vsh[32 * VST];     // [d][k] 14848 B
    __shared__ __align__(16) ushort psh[4][16 * VST];  // per-wave P [q][k] 29696 B

    int blk = blockIdx.x;              // BB * 49
    int b = blk / 49;
    int q0 = (blk % 49) * 64;
    int tid = threadIdx.x;
    int w = tid >> 6, l = tid & 63;
    int lr = l & 15, lg = l >> 4;

    for (int i = tid; i < GKC; i += 256) {
        ushort* kr = &ksh[i * KST];
        kr[27] = 0; kr[28] = 0; kr[29] = 0; kr[30] = 0; kr[31] = 0;
        vsh[27 * VST + i] = 0x3f80;    // bf16 1.0
        vsh[28 * VST + i] = 0; vsh[29 * VST + i] = 0;
        vsh[30 * VST + i] = 0; vsh[31 * VST + i] = 0;
    }

    short8 aq;
    {
        const float* qr = qg + ((size_t)b * GG + q0 + w * 16 + lr) * 27;
#pragma unroll
        for (int j = 0; j < 8; j++) {
            int c = 8 * lg + j;
            aq[j] = (c < 27) ? (short)f2bf(qr[c]) : (short)0;
        }
    }

    f32x4 acc_h0 = {0.f, 0.f, 0.f, 0.f};
    f32x4 acc_h1 = {0.f, 0.f, 0.f, 0.f};
    ushort* myps = &psh[w][0];
    const float* kgb = kg + (size_t)b * GG * 27;
    const float* vgb = vg + (size_t)b * GG * 27;

    for (int ch = 0; ch < 14; ch++) {
        __syncthreads();
        int base = ch * GKC * 27;
        for (int idx = tid; idx < GKC * 27; idx += 256) {
            int kk = idx / 27, c = idx - (idx / 27) * 27;
            ksh[kk * KST + c] = f2bf(kgb[base + idx]);
            vsh[c * VST + kk] = f2bf(vgb[base + idx]);
        }
        __syncthreads();

        f32x4 s[14];
#pragma unroll
        for (int ct = 0; ct < 14; ct++) {
            const short8 bk = *reinterpret_cast<const short8*>(
                &ksh[(ct * 16 + lr) * KST + 8 * lg]);
            s[ct] = __builtin_amdgcn_mfma_f32_16x16x32_bf16(
                aq, bk, (f32x4){0.f, 0.f, 0.f, 0.f}, 0, 0, 0);
        }
#pragma unroll
        for (int ct = 0; ct < 14; ct++) {
#pragma unroll
            for (int r = 0; r < 4; r++) {
                float p = __expf(s[ct][r] * SCALE_G);
                myps[(4 * lg + r) * VST + ct * 16 + lr] = f2bf(p);
            }
        }
#pragma unroll
        for (int kstep = 0; kstep < 7; kstep++) {
            const short8 ap = *reinterpret_cast<const short8*>(
                &myps[lr * VST + kstep * 32 + 8 * lg]);
            const short8 bv0 = *reinterpret_cast<const short8*>(
                &vsh[lr * VST + kstep * 32 + 8 * lg]);
            const short8 bv1 = *reinterpret_cast<const short8*>(
                &vsh[(16 + lr) * VST + kstep * 32 + 8 * lg]);
            acc_h0 = __builtin_amdgcn_mfma_f32_16x16x32_bf16(ap, bv0, acc_h0, 0, 0, 0);
            acc_h1 = __builtin_amdgcn_mfma_f32_16x16x32_bf16(ap, bv1, acc_h1, 0, 0, 0);
        }
    }

#pragma unroll
    for (int r = 0; r < 4; r++) {
        float lsum = __shfl(acc_h1[r], (l & 48) | 11, 64);
        float inv = 1.f / lsum;
        int q = q0 + w * 16 + 4 * lg + r;
        float* hr = hg + ((size_t)b * GG + q) * 27;
        hr[lr] = acc_h0[r] * inv;
        if (lr < 11) hr[16 + lr] = acc_h1[r] * inv;
    }
}

// ---------------- 6. h_patch GEMM via MFMA + bf16-LDS coalesced epilogue ----------------
// 128 threads (2 waves), 32 d-rows, grid BB*864 = 3456 blocks (~13.5 blocks/CU)
// -> enough resident waves to hide latency. hbuf 13056 B.
__global__ __launch_bounds__(128)
void k_hp_fused(const __hip_bfloat16* __restrict__ v, const __hip_bfloat16* __restrict__ whf,
                const float* __restrict__ x, const float* __restrict__ hg,
                float* __restrict__ out) {
    __shared__ __align__(16) ushort hbuf[32 * HST];   // 13056 B
    int blk = blockIdx.x;              // BB * 864
    int b = blk / 864;
    int sub = blk % 864;               // 32-d-row group
    int tid = threadIdx.x;
    int w = tid >> 6, l = tid & 63;    // w in {0,1}
    int ar = l & 15;                   // A row within tile / B col
    int kg = l >> 4;                   // k-group
    int D0 = (sub * 2 + w) * 16;       // d-tile base

    const ushort* vb = (const ushort*)v + (size_t)b * CHW;
    const ushort* wf = (const ushort*)whf + (size_t)b * WFRAG;

    // prefetch all 7 A fragments (V row D0+ar, 56B overread covered by zero tail)
    const ushort* arow = vb + (size_t)(D0 + ar) * NP;
    short8 av[7];
#pragma unroll
    for (int step = 0; step < 7; ++step) {
        int joff = step * 32 + kg * 8;
        ushort4 alo = *reinterpret_cast<const ushort4*>(arow + joff);
        ushort4 ahi = *reinterpret_cast<const ushort4*>(arow + joff + 4);
        av[step][0] = alo.x; av[step][1] = alo.y; av[step][2] = alo.z; av[step][3] = alo.w;
        av[step][4] = ahi.x; av[step][5] = ahi.y; av[step][6] = ahi.z; av[step][7] = ahi.w;
    }

    f32x4 acc[13];
#pragma unroll
    for (int ct = 0; ct < 13; ct++) acc[ct] = (f32x4){0.f, 0.f, 0.f, 0.f};

#pragma unroll
    for (int step = 0; step < 7; ++step) {
        short8 bv[13];
#pragma unroll
        for (int ct = 0; ct < 13; ct++)
            bv[ct] = *reinterpret_cast<const short8*>(
                wf + (((size_t)(step * 13 + ct) * 64 + l) << 3));
#pragma unroll
        for (int ct = 0; ct < 13; ct++)
            acc[ct] = __builtin_amdgcn_mfma_f32_16x16x32_bf16(av[step], bv[ct], acc[ct], 0, 0, 0);
    }

    // stage into LDS (bf16): local row = w*16 + kg*4 + r, col = i (< 196)
#pragma unroll
    for (int ct = 0; ct < 13; ct++) {
        int i = ct * 16 + ar;
        if (i < NP) {
#pragma unroll
            for (int r = 0; r < 4; r++)
                hbuf[(w * 16 + kg * 4 + r) * HST + i] = f2bf(acc[ct][r]);
        }
    }
    __syncthreads();

    // coalesced epilogue over 6272 consecutive pixels of channel c
    int c = sub >> 5;                      // (sub*32) >> 10
    int pix0 = (sub & 31) * 32 * NP;       // strip_base * 196
    const float* xb = x + (size_t)b * CHW + (size_t)c * HW + pix0;
    float* ob = out + (size_t)b * CHW + (size_t)c * HW + pix0;
    const float* hgb = hg + (size_t)b * GG * 27;
    for (int idx4 = tid; idx4 < 1568; idx4 += 128) {
        int j = idx4 * 4;
        int sl = j / NP;                   // local strip
        int i = j - sl * NP;
        ushort4 hv = *reinterpret_cast<const ushort4*>(&hbuf[sl * HST + i]);
        int pix = pix0 + j;
        int h = pix / 448;
        int w2 = pix - h * 448;
        int g = (h >> 3) * 56 + (w2 >> 3);
        float hgs = 0.25f * hgb[g * 27 + c];
        float4 xv = *reinterpret_cast<const float4*>(&xb[j]);
        float4 ov;
        ov.x = xv.x + 0.75f * bf2f(hv.x) + hgs;
        ov.y = xv.y + 0.75f * bf2f(hv.y) + hgs;
        ov.z = xv.z + 0.75f * bf2f(hv.z) + hgs;
        ov.w = xv.w + 0.75f * bf2f(hv.w) + hgs;
        *reinterpret_cast<float4*>(&ob[j]) = ov;
    }
}

// ---------------- launch ----------------
extern "C" void kernel_launch(void* const* d_in, const int* in_sizes, int n_in,
                              void* d_out, int out_size, void* d_ws, size_t ws_size,
                              hipStream_t stream) {
    const float* x    = (const float*)d_in[0];
    const float* gnw  = (const float*)d_in[1];
    const float* gnb  = (const float*)d_in[2];
    const float* qw   = (const float*)d_in[3];
    const float* qb   = (const float*)d_in[4];
    const float* kw   = (const float*)d_in[5];
    const float* kb   = (const float*)d_in[6];
    const float* vw   = (const float*)d_in[7];
    const float* vb   = (const float*)d_in[8];
    const float* pjw  = (const float*)d_in[9];
    float* out = (float*)d_out;

    char* ws = (char*)d_ws;
    size_t off = 0;
    auto alloc = [&](size_t bytes) { void* p = ws + off; off += (bytes + 255) & ~(size_t)255; return p; };
    // qkv: contiguous [3][BB][27][HW] bf16 + 64B zero tail (k_hp_fused overread)
    __hip_bfloat16* qkvbuf = (__hip_bfloat16*)alloc((size_t)3 * BB * CHW * 2 + 64);
    __hip_bfloat16* qbf = qkvbuf;
    __hip_bfloat16* kbf = qkvbuf + (size_t)BB * CHW;
    __hip_bfloat16* vbf = qkvbuf + (size_t)2 * BB * CHW;
    float* spart = (float*)alloc((size_t)BB * NKS * NP * MPAD * 4);
    __hip_bfloat16* wHat = (__hip_bfloat16*)alloc((size_t)BB * WFRAG * 2);
    float* qg    = (float*)alloc((size_t)BB * GG * 27 * 4);
    float* kg    = (float*)alloc((size_t)BB * GG * 27 * 4);
    float* vg    = (float*)alloc((size_t)BB * GG * 27 * 4);
    float* hg    = (float*)alloc((size_t)BB * GG * 27 * 4);
    float* part  = (float*)alloc((size_t)BB * 1024 * 2 * 4);
    float* stats = (float*)alloc((size_t)BB * 2 * 4);
    float* pvw   = (float*)alloc(729 * 4);
    float* pvb   = (float*)alloc(27 * 4);

    (void)hipMemsetAsync((char*)qkvbuf + (size_t)3 * BB * CHW * 2, 0, 64, stream);
    k_fold<<<1, 256, 0, stream>>>(pjw, vw, vb, pvw, pvb);
    k_gn_partial<<<BB * 1024, 256, 0, stream>>>(x, part);
    k_gn_final<<<BB, 256, 0, stream>>>(part, stats);
    k_qkv_mfma<<<(BB * HW) / 256, 256, 0, stream>>>(x, stats, qw, qb, kw, kb, pvw, pvb,
                                                    gnw, gnb, qkvbuf);
    k_pool<<<(BB * 27 * GG) / 256, 256, 0, stream>>>(qbf, qg);
    k_pool<<<(BB * 27 * GG) / 256, 256, 0, stream>>>(kbf, kg);
    k_pool<<<(BB * 27 * GG) / 256, 256, 0, stream>>>(vbf, vg);
    k_spart_mfma<<<BB * NKS, 448, 0, stream>>>(qbf, kbf, spart);
    k_softmax<<<BB * NP, 256, 0, stream>>>(spart, wHat);
    k_gattn_flash<<<BB * 49, 256, 0, stream>>>(qg, kg, vg, hg);
    k_hp_fused<<<BB * 864, 128, 0, stream>>>(vbf, wHat, x, hg, out);
}

// Round 17
// 282.119 us; speedup vs baseline: 1.0627x; 1.0627x over previous
//
#include <hip/hip_runtime.h>
#include <hip/hip_bf16.h>
#include <cstdint>

// ---------------- problem constants ----------------
namespace {
constexpr int BB = 4;
constexpr int CC = 27;
constexpr int HW = 448 * 448;                 // 200704
constexpr long long CHW = (long long)CC * HW; // 5419008
constexpr int NP = 196;                        // patch positions
constexpr int GG = 56 * 56;                    // 3136 pooled positions
constexpr int DTOT = CC * 1024;                // 27648
constexpr float SCALE_P = 0.0060140449f;       // 1/sqrt(27648)
constexpr float SCALE_G = 0.1924500897f;       // 1/sqrt(27)
constexpr float EPSV = 1e-5f;
// MFMA spart config
constexpr int KCH = 512;                       // d-chunk per block
constexpr int NKS = DTOT / KCH;                // 54 partials
constexpr int MPAD = 224;                      // padded n/m (14 tiles of 16)
constexpr int ROWB = 128;                      // LDS bytes per row
// wHat fragment-major, step-major: [7 step][13 ct][64 lane][8 elem] bf16 = 46592 elems
constexpr int WFRAG = 7 * 13 * 64 * 8;
// qkv-MFMA config
constexpr int XST = 40;                        // LDS row stride (shorts)
// flash gattn config
constexpr int GKC = 224;                       // keys per chunk (14 chunks)
constexpr int KST = 40;                        // ks row stride (shorts)
constexpr int VST = 232;                       // vs/ps row stride (shorts)
// hp epilogue LDS stride (shorts, bf16)
constexpr int HST = 204;
}

typedef __attribute__((ext_vector_type(8))) short short8;
typedef __attribute__((ext_vector_type(4))) float f32x4;

__device__ __forceinline__ float bf2f(unsigned short u) {
    return __uint_as_float(((uint32_t)u) << 16);
}

__device__ __forceinline__ ushort f2bf(float f) {
    union { __hip_bfloat16 h; ushort u; } cv;
    cv.h = __float2bfloat16(f);
    return cv.u;
}

// ---------------- 0. fold proj into V weights: pvw = proj*vw, pvb = proj*vb ----------------
__global__ void k_fold(const float* __restrict__ pjw, const float* __restrict__ vw,
                       const float* __restrict__ vb, float* __restrict__ pvw,
                       float* __restrict__ pvb) {
    __shared__ float pj[729], vv[729], vbs[27];
    int t = threadIdx.x;
    for (int i = t; i < 729; i += 256) { pj[i] = pjw[i]; vv[i] = vw[i]; }
    if (t < 27) vbs[t] = vb[t];
    __syncthreads();
    for (int i = t; i < 729; i += 256) {
        int o = i / 27, c2 = i - (i / 27) * 27;
        float s = 0.f;
#pragma unroll
        for (int c = 0; c < 27; c++) s += pj[o * 27 + c] * vv[c * 27 + c2];
        pvw[i] = s;
    }
    if (t < 27) {
        float s = 0.f;
#pragma unroll
        for (int c = 0; c < 27; c++) s += pj[t * 27 + c] * vbs[c];
        pvb[t] = s;
    }
}

// ---------------- 1. GroupNorm stats ----------------
__global__ void k_gn_partial(const float* __restrict__ x, float* __restrict__ part) {
    int blk = blockIdx.x;          // BB*1024 blocks
    int b = blk >> 10;
    int chunk = blk & 1023;
    const int CLEN = (int)(CHW / 1024);   // 5292
    const float* p = x + (size_t)b * CHW + (size_t)chunk * CLEN;
    float s = 0.f, ss = 0.f;
    for (int i = threadIdx.x; i < CLEN; i += 256) {
        float v = p[i];
        s += v; ss += v * v;
    }
    for (int o = 32; o; o >>= 1) { s += __shfl_down(s, o); ss += __shfl_down(ss, o); }
    __shared__ float ls[4], lss[4];
    int wid = threadIdx.x >> 6, lane = threadIdx.x & 63;
    if (lane == 0) { ls[wid] = s; lss[wid] = ss; }
    __syncthreads();
    if (threadIdx.x == 0) {
        float S = ls[0] + ls[1] + ls[2] + ls[3];
        float SS = lss[0] + lss[1] + lss[2] + lss[3];
        part[blk * 2] = S; part[blk * 2 + 1] = SS;
    }
}

__global__ void k_gn_final(const float* __restrict__ part, float* __restrict__ stats) {
    int b = blockIdx.x;
    float s = 0.f, ss = 0.f;
    for (int i = threadIdx.x; i < 1024; i += 256) {
        s += part[(b * 1024 + i) * 2];
        ss += part[(b * 1024 + i) * 2 + 1];
    }
    for (int o = 32; o; o >>= 1) { s += __shfl_down(s, o); ss += __shfl_down(ss, o); }
    __shared__ float ls[4], lss[4];
    int wid = threadIdx.x >> 6, lane = threadIdx.x & 63;
    if (lane == 0) { ls[wid] = s; lss[wid] = ss; }
    __syncthreads();
    if (threadIdx.x == 0) {
        float S = ls[0] + ls[1] + ls[2] + ls[3];
        float SS = lss[0] + lss[1] + lss[2] + lss[3];
        float mean = S / (float)CHW;
        float var = SS / (float)CHW - mean * mean;
        stats[b * 2] = mean;
        stats[b * 2 + 1] = rsqrtf(var + EPSV);
    }
}

// ---------------- 2. GN-apply + QKV conv1x1 via MFMA (-> bf16) ----------------
__global__ __launch_bounds__(256, 2)
void k_qkv_mfma(const float* __restrict__ x, const float* __restrict__ stats,
                const float* __restrict__ qw, const float* __restrict__ qb,
                const float* __restrict__ kw, const float* __restrict__ kb,
                const float* __restrict__ vw, const float* __restrict__ vb,
                const float* __restrict__ gnw, const float* __restrict__ gnb,
                __hip_bfloat16* __restrict__ qkv) {
    __shared__ ushort xs[256 * XST];            // 20480 B
    __shared__ ushort wls[96 * XST];            // 7680 B
    __shared__ __align__(16) float bls[96];
    __shared__ float gwls[27], gbls[27];

    int tid = threadIdx.x;
    int P0 = blockIdx.x * 256;                  // global pixel base
    int b = P0 / HW;                            // HW % 256 == 0: no straddle
    int hw0 = P0 - b * HW;

    for (int i = tid; i < 96 * 32; i += 256) {
        int row = i >> 5, c = i & 31;
        float wv = 0.f;
        if (c < 27 && row < 81) {
            int t = (row >= 54) ? 2 : (row >= 27 ? 1 : 0);
            int oc = row - t * 27;
            const float* wp = (t == 0) ? qw : (t == 1) ? kw : vw;
            wv = wp[oc * 27 + c];
        }
        wls[row * XST + c] = f2bf(wv);
    }
    if (tid < 96) {
        float bv = 0.f;
        if (tid < 27) bv = qb[tid];
        else if (tid < 54) bv = kb[tid - 27];
        else if (tid < 81) bv = vb[tid - 54];
        bls[tid] = bv;
    }
    if (tid < 27) { gwls[tid] = gnw[tid]; gbls[tid] = gnb[tid]; }
    float mean = stats[b * 2], rstd = stats[b * 2 + 1];
    __syncthreads();

    {
        const float* xp = x + (size_t)b * CHW + hw0 + tid;
        ushort xv[28];
#pragma unroll
        for (int c = 0; c < 27; c++) {
            float v = (xp[(size_t)c * HW] - mean) * rstd * gwls[c] + gbls[c];
            xv[c] = f2bf(v);
        }
        xv[27] = 0;
        uint32_t* xrow = reinterpret_cast<uint32_t*>(&xs[tid * XST]);
#pragma unroll
        for (int i = 0; i < 14; i++)
            xrow[i] = (uint32_t)xv[2 * i] | ((uint32_t)xv[2 * i + 1] << 16);
        xrow[14] = 0; xrow[15] = 0;
    }
    __syncthreads();

    int w = tid >> 6, l = tid & 63;
    int lrow = l & 15, kg = l >> 4;

    short8 afr[6];
    f32x4 binit[6];
#pragma unroll
    for (int mt = 0; mt < 6; mt++) {
        afr[mt] = *reinterpret_cast<const short8*>(&wls[(mt * 16 + lrow) * XST + kg * 8]);
        binit[mt] = *reinterpret_cast<const f32x4*>(&bls[mt * 16 + kg * 4]);
    }

    f32x4 acc[4][6];
#pragma unroll
    for (int pt = 0; pt < 4; pt++) {
        const short8 bfr = *reinterpret_cast<const short8*>(
            &xs[(w * 64 + pt * 16 + lrow) * XST + kg * 8]);
#pragma unroll
        for (int mt = 0; mt < 6; mt++)
            acc[pt][mt] = __builtin_amdgcn_mfma_f32_16x16x32_bf16(afr[mt], bfr, binit[mt], 0, 0, 0);
    }

    ushort* ob = (ushort*)qkv;
#pragma unroll
    for (int pt = 0; pt < 4; pt++) {
        int hw = hw0 + w * 64 + pt * 16 + lrow;
#pragma unroll
        for (int mt = 0; mt < 6; mt++) {
#pragma unroll
            for (int r = 0; r < 4; r++) {
                int o = mt * 16 + kg * 4 + r;
                if (o < 81) {
                    int t = (o >= 54) ? 2 : (o >= 27 ? 1 : 0);
                    int oc = o - t * 27;
                    ob[((size_t)t * BB + b) * CHW + (size_t)oc * HW + hw] = f2bf(acc[pt][mt][r]);
                }
            }
        }
    }
}

// ---------------- 3. 8x8 avg pool -> transposed [b][g][27] ----------------
__global__ void k_pool(const __hip_bfloat16* __restrict__ src, float* __restrict__ dst) {
    int idx = blockIdx.x * 256 + threadIdx.x;  // < 4*27*3136 = 338688
    int g = idx % GG;
    int t = idx / GG;
    int c = t % 27;
    int b = t / 27;
    int gh = g / 56, gw = g - (g / 56) * 56;
    const ushort* sp = (const ushort*)src + (size_t)(b * 27 + c) * HW + (size_t)(gh * 8) * 448 + gw * 8;
    float s = 0.f;
#pragma unroll
    for (int r = 0; r < 8; r++) {
        const ushort4 a = *reinterpret_cast<const ushort4*>(sp + r * 448);
        const ushort4 d = *reinterpret_cast<const ushort4*>(sp + r * 448 + 4);
        s += bf2f(a.x) + bf2f(a.y) + bf2f(a.z) + bf2f(a.w)
           + bf2f(d.x) + bf2f(d.y) + bf2f(d.z) + bf2f(d.w);
    }
    dst[((size_t)b * GG + g) * 27 + c] = s * (1.f / 64.f);
}

// ---------------- 4a. patch attention S partials via MFMA ----------------
__global__ __launch_bounds__(448, 1)
void k_spart_mfma(const __hip_bfloat16* __restrict__ q, const __hip_bfloat16* __restrict__ k,
                  float* __restrict__ spart) {
    __shared__ ushort lq[MPAD * 64];   // 28672 B
    __shared__ ushort lk[MPAD * 64];
    int blk = blockIdx.x;              // 4b * 54ks = 216
    int ks = blk % NKS;
    int b = blk / NKS;
    const ushort* qb_ = (const ushort*)q + (size_t)b * CHW;
    const ushort* kb_ = (const ushort*)k + (size_t)b * CHW;
    int t = threadIdx.x;
    int w = t >> 6, l = t & 63;
    int lrow = l & 15, lg = l >> 4;    // fragment coords
    int sr = t & 15;                   // d-pair index 0..15 (d = 2sr, 2sr+1)
    int sn8 = t >> 4;                  // col-chunk 0..27 (cols sn8*8..+8)

    f32x4 acc[2][13];
#pragma unroll
    for (int i = 0; i < 2; i++)
#pragma unroll
        for (int ct = 0; ct < 13; ct++) acc[i][ct] = (f32x4){0.f, 0.f, 0.f, 0.f};

    int d0 = ks * KCH;
    for (int step = 0; step < KCH / 32; ++step) {
        int dbase = d0 + step * 32;
        {
            const ushort* s0 = qb_ + (size_t)(dbase + 2 * sr) * NP + sn8 * 8;
            const ushort* s1 = s0 + NP;
            ushort4 a0 = *reinterpret_cast<const ushort4*>(s0);
            ushort4 a1 = *reinterpret_cast<const ushort4*>(s0 + 4);
            ushort4 b0 = *reinterpret_cast<const ushort4*>(s1);
            ushort4 b1 = *reinterpret_cast<const ushort4*>(s1 + 4);
            ushort ra[8] = {a0.x, a0.y, a0.z, a0.w, a1.x, a1.y, a1.z, a1.w};
            ushort rb[8] = {b0.x, b0.y, b0.z, b0.w, b1.x, b1.y, b1.z, b1.w};
#pragma unroll
            for (int kk = 0; kk < 8; kk++) {
                int n = sn8 * 8 + kk;
                uint32_t val = (uint32_t)ra[kk] | ((uint32_t)rb[kk] << 16);
                *reinterpret_cast<uint32_t*>(reinterpret_cast<char*>(lq) + n * ROWB +
                                             ((4 * sr) ^ (16 * (n & 7)))) = val;
            }
        }
        {
            const ushort* s0 = kb_ + (size_t)(dbase + 2 * sr) * NP + sn8 * 8;
            const ushort* s1 = s0 + NP;
            ushort4 a0 = *reinterpret_cast<const ushort4*>(s0);
            ushort4 a1 = *reinterpret_cast<const ushort4*>(s0 + 4);
            ushort4 b0 = *reinterpret_cast<const ushort4*>(s1);
            ushort4 b1 = *reinterpret_cast<const ushort4*>(s1 + 4);
            ushort ra[8] = {a0.x, a0.y, a0.z, a0.w, a1.x, a1.y, a1.z, a1.w};
            ushort rb[8] = {b0.x, b0.y, b0.z, b0.w, b1.x, b1.y, b1.z, b1.w};
#pragma unroll
            for (int kk = 0; kk < 8; kk++) {
                int m = sn8 * 8 + kk;
                uint32_t val = (uint32_t)ra[kk] | ((uint32_t)rb[kk] << 16);
                *reinterpret_cast<uint32_t*>(reinterpret_cast<char*>(lk) + m * ROWB +
                                             ((4 * sr) ^ (16 * (m & 7)))) = val;
            }
        }
        __syncthreads();
        int nA0 = (2 * w) * 16 + lrow;
        int nA1 = nA0 + 16;
        const short8 afr0 = *reinterpret_cast<const short8*>(
            reinterpret_cast<const char*>(lq) + nA0 * ROWB + 16 * (lg ^ (nA0 & 7)));
        const short8 afr1 = *reinterpret_cast<const short8*>(
            reinterpret_cast<const char*>(lq) + nA1 * ROWB + 16 * (lg ^ (nA1 & 7)));
#pragma unroll
        for (int ct = 0; ct < 13; ct++) {
            int m = ct * 16 + lrow;
            const short8 bfr = *reinterpret_cast<const short8*>(
                reinterpret_cast<const char*>(lk) + m * ROWB + 16 * (lg ^ (m & 7)));
            acc[0][ct] = __builtin_amdgcn_mfma_f32_16x16x32_bf16(afr0, bfr, acc[0][ct], 0, 0, 0);
            acc[1][ct] = __builtin_amdgcn_mfma_f32_16x16x32_bf16(afr1, bfr, acc[1][ct], 0, 0, 0);
        }
        __syncthreads();
    }
    float* sp = spart + (size_t)(b * NKS + ks) * NP * MPAD;
#pragma unroll
    for (int i = 0; i < 2; i++) {
        int rt = 2 * w + i;
#pragma unroll
        for (int r = 0; r < 4; r++) {
            int n = rt * 16 + lg * 4 + r;
            if (n < NP) {
#pragma unroll
                for (int ct = 0; ct < 13; ct++)
                    sp[(size_t)n * MPAD + ct * 16 + lrow] = acc[i][ct][r];
            }
        }
    }
}

// ---------------- 4b. reduce + row softmax -> whf fragment-major (step-major) bf16 ----------------
__global__ void k_softmax(const float* __restrict__ spart, __hip_bfloat16* __restrict__ whf) {
    int blk = blockIdx.x;        // BB*196
    int n = blk % NP;            // query row
    int b = blk / NP;
    int m = threadIdx.x;         // key col
    float val = -1e30f;
    if (m < 196) {
        float s = 0.f;
        for (int ks = 0; ks < NKS; ks++)
            s += spart[((size_t)(b * NKS + ks) * NP + n) * MPAD + m];
        val = s * SCALE_P;
    }
    float mx = val;
    for (int o = 32; o; o >>= 1) mx = fmaxf(mx, __shfl_xor(mx, o));
    __shared__ float redm[4], reds[4];
    int wid = threadIdx.x >> 6, lane = threadIdx.x & 63;
    if (lane == 0) redm[wid] = mx;
    __syncthreads();
    mx = fmaxf(fmaxf(redm[0], redm[1]), fmaxf(redm[2], redm[3]));
    float p = (m < 196) ? __expf(val - mx) : 0.f;
    float sm = p;
    for (int o = 32; o; o >>= 1) sm += __shfl_xor(sm, o);
    if (lane == 0) reds[wid] = sm;
    __syncthreads();
    sm = reds[0] + reds[1] + reds[2] + reds[3];
    if (m < 224) {
        int ct = n >> 4, lr = n & 15;
        int step = m >> 5, kg = (m >> 3) & 3, e = m & 7;
        size_t addr = (size_t)b * WFRAG +
                      (((size_t)(step * 13 + ct) * 64 + kg * 16 + lr) << 3) + e;
        whf[addr] = __float2bfloat16((m < 196) ? p / sm : 0.f);
    }
}

// ---------------- 5. global pooled attention: flash MFMA ----------------
__global__ __launch_bounds__(256)
void k_gattn_flash(const float* __restrict__ qg, const float* __restrict__ kg,
                   const float* __restrict__ vg, float* __restrict__ hg) {
    __shared__ __align__(16) ushort ksh[GKC * KST];    // [k][d] 17920 B
    __shared__ __align__(16) ushort vsh[32 * VST];     // [d][k] 14848 B
    __shared__ __align__(16) ushort psh[4][16 * VST];  // per-wave P [q][k] 29696 B

    int blk = blockIdx.x;              // BB * 49
    int b = blk / 49;
    int q0 = (blk % 49) * 64;
    int tid = threadIdx.x;
    int w = tid >> 6, l = tid & 63;
    int lr = l & 15, lg = l >> 4;

    for (int i = tid; i < GKC; i += 256) {
        ushort* kr = &ksh[i * KST];
        kr[27] = 0; kr[28] = 0; kr[29] = 0; kr[30] = 0; kr[31] = 0;
        vsh[27 * VST + i] = 0x3f80;    // bf16 1.0
        vsh[28 * VST + i] = 0; vsh[29 * VST + i] = 0;
        vsh[30 * VST + i] = 0; vsh[31 * VST + i] = 0;
    }

    short8 aq;
    {
        const float* qr = qg + ((size_t)b * GG + q0 + w * 16 + lr) * 27;
#pragma unroll
        for (int j = 0; j < 8; j++) {
            int c = 8 * lg + j;
            aq[j] = (c < 27) ? (short)f2bf(qr[c]) : (short)0;
        }
    }

    f32x4 acc_h0 = {0.f, 0.f, 0.f, 0.f};
    f32x4 acc_h1 = {0.f, 0.f, 0.f, 0.f};
    ushort* myps = &psh[w][0];
    const float* kgb = kg + (size_t)b * GG * 27;
    const float* vgb = vg + (size_t)b * GG * 27;

    for (int ch = 0; ch < 14; ch++) {
        __syncthreads();
        int base = ch * GKC * 27;
        for (int idx = tid; idx < GKC * 27; idx += 256) {
            int kk = idx / 27, c = idx - (idx / 27) * 27;
            ksh[kk * KST + c] = f2bf(kgb[base + idx]);
            vsh[c * VST + kk] = f2bf(vgb[base + idx]);
        }
        __syncthreads();

        f32x4 s[14];
#pragma unroll
        for (int ct = 0; ct < 14; ct++) {
            const short8 bk = *reinterpret_cast<const short8*>(
                &ksh[(ct * 16 + lr) * KST + 8 * lg]);
            s[ct] = __builtin_amdgcn_mfma_f32_16x16x32_bf16(
                aq, bk, (f32x4){0.f, 0.f, 0.f, 0.f}, 0, 0, 0);
        }
#pragma unroll
        for (int ct = 0; ct < 14; ct++) {
#pragma unroll
            for (int r = 0; r < 4; r++) {
                float p = __expf(s[ct][r] * SCALE_G);
                myps[(4 * lg + r) * VST + ct * 16 + lr] = f2bf(p);
            }
        }
#pragma unroll
        for (int kstep = 0; kstep < 7; kstep++) {
            const short8 ap = *reinterpret_cast<const short8*>(
                &myps[lr * VST + kstep * 32 + 8 * lg]);
            const short8 bv0 = *reinterpret_cast<const short8*>(
                &vsh[lr * VST + kstep * 32 + 8 * lg]);
            const short8 bv1 = *reinterpret_cast<const short8*>(
                &vsh[(16 + lr) * VST + kstep * 32 + 8 * lg]);
            acc_h0 = __builtin_amdgcn_mfma_f32_16x16x32_bf16(ap, bv0, acc_h0, 0, 0, 0);
            acc_h1 = __builtin_amdgcn_mfma_f32_16x16x32_bf16(ap, bv1, acc_h1, 0, 0, 0);
        }
    }

#pragma unroll
    for (int r = 0; r < 4; r++) {
        float lsum = __shfl(acc_h1[r], (l & 48) | 11, 64);
        float inv = 1.f / lsum;
        int q = q0 + w * 16 + 4 * lg + r;
        float* hr = hg + ((size_t)b * GG + q) * 27;
        hr[lr] = acc_h0[r] * inv;
        if (lr < 11) hr[16 + lr] = acc_h1[r] * inv;
    }
}

// ---------------- 6. h_patch GEMM via MFMA + bf16-LDS coalesced epilogue ----------------
// 256 threads; XCD-swizzled grid (1728 % 8 == 0); x prefetched into registers at
// kernel start so its HBM latency hides under the MFMA + staging phase (T14).
__global__ __launch_bounds__(256)
void k_hp_fused(const __hip_bfloat16* __restrict__ v, const __hip_bfloat16* __restrict__ whf,
                const float* __restrict__ x, const float* __restrict__ hg,
                float* __restrict__ out) {
    __shared__ __align__(16) ushort hbuf[64 * HST];   // 26112 B
    int nper = gridDim.x >> 3;         // 216
    int bid = blockIdx.x;
    int blk = (bid & 7) * nper + (bid >> 3);   // bijective XCD swizzle
    int b = blk / 432;
    int grp = blk % 432;
    int tid = threadIdx.x;
    int w = tid >> 6, l = tid & 63;
    int ar = l & 15;                   // A row within tile / B col
    int kg = l >> 4;                   // k-group
    int D0 = (grp * 4 + w) * 16;       // d-tile base

    // ---- early x prefetch (epilogue operand): 12 full rounds of 256 threads ----
    int c = grp >> 4;                      // (grp*64) >> 10
    int pix0 = (grp & 15) * 64 * NP;       // strip_base * 196
    const float* xb = x + (size_t)b * CHW + (size_t)c * HW + pix0;
    float4 xpre[12];
#pragma unroll
    for (int it = 0; it < 12; ++it)
        xpre[it] = *reinterpret_cast<const float4*>(&xb[(tid + it * 256) * 4]);

    const ushort* vb = (const ushort*)v + (size_t)b * CHW;
    const ushort* wf = (const ushort*)whf + (size_t)b * WFRAG;

    // prefetch all 7 A fragments (V row D0+ar, 56B overread covered by zero tail)
    const ushort* arow = vb + (size_t)(D0 + ar) * NP;
    short8 av[7];
#pragma unroll
    for (int step = 0; step < 7; ++step) {
        int joff = step * 32 + kg * 8;
        ushort4 alo = *reinterpret_cast<const ushort4*>(arow + joff);
        ushort4 ahi = *reinterpret_cast<const ushort4*>(arow + joff + 4);
        av[step][0] = alo.x; av[step][1] = alo.y; av[step][2] = alo.z; av[step][3] = alo.w;
        av[step][4] = ahi.x; av[step][5] = ahi.y; av[step][6] = ahi.z; av[step][7] = ahi.w;
    }

    f32x4 acc[13];
#pragma unroll
    for (int ct = 0; ct < 13; ct++) acc[ct] = (f32x4){0.f, 0.f, 0.f, 0.f};

#pragma unroll
    for (int step = 0; step < 7; ++step) {
        short8 bv[13];
#pragma unroll
        for (int ct = 0; ct < 13; ct++)
            bv[ct] = *reinterpret_cast<const short8*>(
                wf + (((size_t)(step * 13 + ct) * 64 + l) << 3));
#pragma unroll
        for (int ct = 0; ct < 13; ct++)
            acc[ct] = __builtin_amdgcn_mfma_f32_16x16x32_bf16(av[step], bv[ct], acc[ct], 0, 0, 0);
    }

    // stage into LDS (bf16): local row = w*16 + kg*4 + r, col = i (< 196)
#pragma unroll
    for (int ct = 0; ct < 13; ct++) {
        int i = ct * 16 + ar;
        if (i < NP) {
#pragma unroll
            for (int r = 0; r < 4; r++)
                hbuf[(w * 16 + kg * 4 + r) * HST + i] = f2bf(acc[ct][r]);
        }
    }
    __syncthreads();

    // coalesced epilogue over 12544 consecutive pixels of channel c
    float* ob = out + (size_t)b * CHW + (size_t)c * HW + pix0;
    const float* hgb = hg + (size_t)b * GG * 27;
#pragma unroll
    for (int it = 0; it < 12; ++it) {
        int idx4 = tid + it * 256;
        int j = idx4 * 4;
        int sl = j / NP;                   // local strip
        int i = j - sl * NP;
        ushort4 hv = *reinterpret_cast<const ushort4*>(&hbuf[sl * HST + i]);
        int pix = pix0 + j;
        int h = pix / 448;
        int w2 = pix - h * 448;
        int g = (h >> 3) * 56 + (w2 >> 3);
        float hgs = 0.25f * hgb[g * 27 + c];
        float4 xv = xpre[it];
        float4 ov;
        ov.x = xv.x + 0.75f * bf2f(hv.x) + hgs;
        ov.y = xv.y + 0.75f * bf2f(hv.y) + hgs;
        ov.z = xv.z + 0.75f * bf2f(hv.z) + hgs;
        ov.w = xv.w + 0.75f * bf2f(hv.w) + hgs;
        *reinterpret_cast<float4*>(&ob[j]) = ov;
    }
    // tail: idx4 in [3072, 3136)
    if (tid < 64) {
        int idx4 = 3072 + tid;
        int j = idx4 * 4;
        int sl = j / NP;
        int i = j - sl * NP;
        ushort4 hv = *reinterpret_cast<const ushort4*>(&hbuf[sl * HST + i]);
        int pix = pix0 + j;
        int h = pix / 448;
        int w2 = pix - h * 448;
        int g = (h >> 3) * 56 + (w2 >> 3);
        float hgs = 0.25f * hgb[g * 27 + c];
        float4 xv = *reinterpret_cast<const float4*>(&xb[j]);
        float4 ov;
        ov.x = xv.x + 0.75f * bf2f(hv.x) + hgs;
        ov.y = xv.y + 0.75f * bf2f(hv.y) + hgs;
        ov.z = xv.z + 0.75f * bf2f(hv.z) + hgs;
        ov.w = xv.w + 0.75f * bf2f(hv.w) + hgs;
        *reinterpret_cast<float4*>(&ob[j]) = ov;
    }
}

// ---------------- launch ----------------
extern "C" void kernel_launch(void* const* d_in, const int* in_sizes, int n_in,
                              void* d_out, int out_size, void* d_ws, size_t ws_size,
                              hipStream_t stream) {
    const float* x    = (const float*)d_in[0];
    const float* gnw  = (const float*)d_in[1];
    const float* gnb  = (const float*)d_in[2];
    const float* qw   = (const float*)d_in[3];
    const float* qb   = (const float*)d_in[4];
    const float* kw   = (const float*)d_in[5];
    const float* kb   = (const float*)d_in[6];
    const float* vw   = (const float*)d_in[7];
    const float* vb   = (const float*)d_in[8];
    const float* pjw  = (const float*)d_in[9];
    float* out = (float*)d_out;

    char* ws = (char*)d_ws;
    size_t off = 0;
    auto alloc = [&](size_t bytes) { void* p = ws + off; off += (bytes + 255) & ~(size_t)255; return p; };
    // qkv: contiguous [3][BB][27][HW] bf16 + 64B zero tail (k_hp_fused overread)
    __hip_bfloat16* qkvbuf = (__hip_bfloat16*)alloc((size_t)3 * BB * CHW * 2 + 64);
    __hip_bfloat16* qbf = qkvbuf;
    __hip_bfloat16* kbf = qkvbuf + (size_t)BB * CHW;
    __hip_bfloat16* vbf = qkvbuf + (size_t)2 * BB * CHW;
    float* spart = (float*)alloc((size_t)BB * NKS * NP * MPAD * 4);
    __hip_bfloat16* wHat = (__hip_bfloat16*)alloc((size_t)BB * WFRAG * 2);
    float* qg    = (float*)alloc((size_t)BB * GG * 27 * 4);
    float* kg    = (float*)alloc((size_t)BB * GG * 27 * 4);
    float* vg    = (float*)alloc((size_t)BB * GG * 27 * 4);
    float* hg    = (float*)alloc((size_t)BB * GG * 27 * 4);
    float* part  = (float*)alloc((size_t)BB * 1024 * 2 * 4);
    float* stats = (float*)alloc((size_t)BB * 2 * 4);
    float* pvw   = (float*)alloc(729 * 4);
    float* pvb   = (float*)alloc(27 * 4);

    (void)hipMemsetAsync((char*)qkvbuf + (size_t)3 * BB * CHW * 2, 0, 64, stream);
    k_fold<<<1, 256, 0, stream>>>(pjw, vw, vb, pvw, pvb);
    k_gn_partial<<<BB * 1024, 256, 0, stream>>>(x, part);
    k_gn_final<<<BB, 256, 0, stream>>>(part, stats);
    k_qkv_mfma<<<(BB * HW) / 256, 256, 0, stream>>>(x, stats, qw, qb, kw, kb, pvw, pvb,
                                                    gnw, gnb, qkvbuf);
    k_pool<<<(BB * 27 * GG) / 256, 256, 0, stream>>>(qbf, qg);
    k_pool<<<(BB * 27 * GG) / 256, 256, 0, stream>>>(kbf, kg);
    k_pool<<<(BB * 27 * GG) / 256, 256, 0, stream>>>(vbf, vg);
    k_spart_mfma<<<BB * NKS, 448, 0, stream>>>(qbf, kbf, spart);
    k_softmax<<<BB * NP, 256, 0, stream>>>(spart, wHat);
    k_gattn_flash<<<BB * 49, 256, 0, stream>>>(qg, kg, vg, hg);
    k_hp_fused<<<BB * 432, 256, 0, stream>>>(vbf, wHat, x, hg, out);
}

// Round 18
// 256.059 us; speedup vs baseline: 1.1709x; 1.1018x over previous
//
#include <hip/hip_runtime.h>
#include <hip/hip_bf16.h>
#include <cstdint>

// ---------------- problem constants ----------------
namespace {
constexpr int BB = 4;
constexpr int CC = 27;
constexpr int HW = 448 * 448;                 // 200704
constexpr long long CHW = (long long)CC * HW; // 5419008
constexpr int NP = 196;                        // patch positions
constexpr int GG = 56 * 56;                    // 3136 pooled positions
constexpr int DTOT = CC * 1024;                // 27648
constexpr float SCALE_P = 0.0060140449f;       // 1/sqrt(27648)
constexpr float SCALE_G = 0.1924500897f;       // 1/sqrt(27)
constexpr float EPSV = 1e-5f;
// MFMA spart config
constexpr int KCH = 512;                       // d-chunk per block
constexpr int NKS = DTOT / KCH;                // 54 partials
constexpr int MPAD = 224;                      // padded n/m (14 tiles of 16)
constexpr int ROWB = 128;                      // LDS bytes per row
// wHat fragment-major, step-major: [7 step][13 ct][64 lane][8 elem] bf16 = 46592 elems
constexpr int WFRAG = 7 * 13 * 64 * 8;
// qkv-MFMA config
constexpr int XST = 40;                        // LDS row stride (shorts)
// flash gattn config
constexpr int GKC = 224;                       // keys per chunk (14 chunks)
constexpr int GKS = 7;                         // key splits (2 chunks per block)
constexpr int KST = 40;                        // ks row stride (shorts)
constexpr int VST = 232;                       // vs/ps row stride (shorts)
// hp epilogue LDS stride (shorts, bf16)
constexpr int HST = 204;
}

typedef __attribute__((ext_vector_type(8))) short short8;
typedef __attribute__((ext_vector_type(4))) float f32x4;

__device__ __forceinline__ float bf2f(unsigned short u) {
    return __uint_as_float(((uint32_t)u) << 16);
}

__device__ __forceinline__ ushort f2bf(float f) {
    union { __hip_bfloat16 h; ushort u; } cv;
    cv.h = __float2bfloat16(f);
    return cv.u;
}

// ---------------- 0. fold proj into V weights: pvw = proj*vw, pvb = proj*vb ----------------
__global__ void k_fold(const float* __restrict__ pjw, const float* __restrict__ vw,
                       const float* __restrict__ vb, float* __restrict__ pvw,
                       float* __restrict__ pvb) {
    __shared__ float pj[729], vv[729], vbs[27];
    int t = threadIdx.x;
    for (int i = t; i < 729; i += 256) { pj[i] = pjw[i]; vv[i] = vw[i]; }
    if (t < 27) vbs[t] = vb[t];
    __syncthreads();
    for (int i = t; i < 729; i += 256) {
        int o = i / 27, c2 = i - (i / 27) * 27;
        float s = 0.f;
#pragma unroll
        for (int c = 0; c < 27; c++) s += pj[o * 27 + c] * vv[c * 27 + c2];
        pvw[i] = s;
    }
    if (t < 27) {
        float s = 0.f;
#pragma unroll
        for (int c = 0; c < 27; c++) s += pj[t * 27 + c] * vbs[c];
        pvb[t] = s;
    }
}

// ---------------- 1. GroupNorm stats ----------------
__global__ void k_gn_partial(const float* __restrict__ x, float* __restrict__ part) {
    int blk = blockIdx.x;          // BB*1024 blocks
    int b = blk >> 10;
    int chunk = blk & 1023;
    const int CLEN = (int)(CHW / 1024);   // 5292
    const float* p = x + (size_t)b * CHW + (size_t)chunk * CLEN;
    float s = 0.f, ss = 0.f;
    for (int i = threadIdx.x; i < CLEN; i += 256) {
        float v = p[i];
        s += v; ss += v * v;
    }
    for (int o = 32; o; o >>= 1) { s += __shfl_down(s, o); ss += __shfl_down(ss, o); }
    __shared__ float ls[4], lss[4];
    int wid = threadIdx.x >> 6, lane = threadIdx.x & 63;
    if (lane == 0) { ls[wid] = s; lss[wid] = ss; }
    __syncthreads();
    if (threadIdx.x == 0) {
        float S = ls[0] + ls[1] + ls[2] + ls[3];
        float SS = lss[0] + lss[1] + lss[2] + lss[3];
        part[blk * 2] = S; part[blk * 2 + 1] = SS;
    }
}

__global__ void k_gn_final(const float* __restrict__ part, float* __restrict__ stats) {
    int b = blockIdx.x;
    float s = 0.f, ss = 0.f;
    for (int i = threadIdx.x; i < 1024; i += 256) {
        s += part[(b * 1024 + i) * 2];
        ss += part[(b * 1024 + i) * 2 + 1];
    }
    for (int o = 32; o; o >>= 1) { s += __shfl_down(s, o); ss += __shfl_down(ss, o); }
    __shared__ float ls[4], lss[4];
    int wid = threadIdx.x >> 6, lane = threadIdx.x & 63;
    if (lane == 0) { ls[wid] = s; lss[wid] = ss; }
    __syncthreads();
    if (threadIdx.x == 0) {
        float S = ls[0] + ls[1] + ls[2] + ls[3];
        float SS = lss[0] + lss[1] + lss[2] + lss[3];
        float mean = S / (float)CHW;
        float var = SS / (float)CHW - mean * mean;
        stats[b * 2] = mean;
        stats[b * 2 + 1] = rsqrtf(var + EPSV);
    }
}

// ---------------- 2. GN-apply + QKV conv1x1 via MFMA (-> bf16) ----------------
__global__ __launch_bounds__(256, 2)
void k_qkv_mfma(const float* __restrict__ x, const float* __restrict__ stats,
                const float* __restrict__ qw, const float* __restrict__ qb,
                const float* __restrict__ kw, const float* __restrict__ kb,
                const float* __restrict__ vw, const float* __restrict__ vb,
                const float* __restrict__ gnw, const float* __restrict__ gnb,
                __hip_bfloat16* __restrict__ qkv) {
    __shared__ ushort xs[256 * XST];            // 20480 B
    __shared__ ushort wls[96 * XST];            // 7680 B
    __shared__ __align__(16) float bls[96];
    __shared__ float gwls[27], gbls[27];

    int tid = threadIdx.x;
    int P0 = blockIdx.x * 256;                  // global pixel base
    int b = P0 / HW;                            // HW % 256 == 0: no straddle
    int hw0 = P0 - b * HW;

    for (int i = tid; i < 96 * 32; i += 256) {
        int row = i >> 5, c = i & 31;
        float wv = 0.f;
        if (c < 27 && row < 81) {
            int t = (row >= 54) ? 2 : (row >= 27 ? 1 : 0);
            int oc = row - t * 27;
            const float* wp = (t == 0) ? qw : (t == 1) ? kw : vw;
            wv = wp[oc * 27 + c];
        }
        wls[row * XST + c] = f2bf(wv);
    }
    if (tid < 96) {
        float bv = 0.f;
        if (tid < 27) bv = qb[tid];
        else if (tid < 54) bv = kb[tid - 27];
        else if (tid < 81) bv = vb[tid - 54];
        bls[tid] = bv;
    }
    if (tid < 27) { gwls[tid] = gnw[tid]; gbls[tid] = gnb[tid]; }
    float mean = stats[b * 2], rstd = stats[b * 2 + 1];
    __syncthreads();

    {
        const float* xp = x + (size_t)b * CHW + hw0 + tid;
        ushort xv[28];
#pragma unroll
        for (int c = 0; c < 27; c++) {
            float v = (xp[(size_t)c * HW] - mean) * rstd * gwls[c] + gbls[c];
            xv[c] = f2bf(v);
        }
        xv[27] = 0;
        uint32_t* xrow = reinterpret_cast<uint32_t*>(&xs[tid * XST]);
#pragma unroll
        for (int i = 0; i < 14; i++)
            xrow[i] = (uint32_t)xv[2 * i] | ((uint32_t)xv[2 * i + 1] << 16);
        xrow[14] = 0; xrow[15] = 0;
    }
    __syncthreads();

    int w = tid >> 6, l = tid & 63;
    int lrow = l & 15, kg = l >> 4;

    short8 afr[6];
    f32x4 binit[6];
#pragma unroll
    for (int mt = 0; mt < 6; mt++) {
        afr[mt] = *reinterpret_cast<const short8*>(&wls[(mt * 16 + lrow) * XST + kg * 8]);
        binit[mt] = *reinterpret_cast<const f32x4*>(&bls[mt * 16 + kg * 4]);
    }

    f32x4 acc[4][6];
#pragma unroll
    for (int pt = 0; pt < 4; pt++) {
        const short8 bfr = *reinterpret_cast<const short8*>(
            &xs[(w * 64 + pt * 16 + lrow) * XST + kg * 8]);
#pragma unroll
        for (int mt = 0; mt < 6; mt++)
            acc[pt][mt] = __builtin_amdgcn_mfma_f32_16x16x32_bf16(afr[mt], bfr, binit[mt], 0, 0, 0);
    }

    ushort* ob = (ushort*)qkv;
#pragma unroll
    for (int pt = 0; pt < 4; pt++) {
        int hw = hw0 + w * 64 + pt * 16 + lrow;
#pragma unroll
        for (int mt = 0; mt < 6; mt++) {
#pragma unroll
            for (int r = 0; r < 4; r++) {
                int o = mt * 16 + kg * 4 + r;
                if (o < 81) {
                    int t = (o >= 54) ? 2 : (o >= 27 ? 1 : 0);
                    int oc = o - t * 27;
                    ob[((size_t)t * BB + b) * CHW + (size_t)oc * HW + hw] = f2bf(acc[pt][mt][r]);
                }
            }
        }
    }
}

// ---------------- 3. 8x8 avg pool -> transposed [b][g][27] ----------------
__global__ void k_pool(const __hip_bfloat16* __restrict__ src, float* __restrict__ dst) {
    int idx = blockIdx.x * 256 + threadIdx.x;  // < 4*27*3136 = 338688
    int g = idx % GG;
    int t = idx / GG;
    int c = t % 27;
    int b = t / 27;
    int gh = g / 56, gw = g - (g / 56) * 56;
    const ushort* sp = (const ushort*)src + (size_t)(b * 27 + c) * HW + (size_t)(gh * 8) * 448 + gw * 8;
    float s = 0.f;
#pragma unroll
    for (int r = 0; r < 8; r++) {
        const ushort4 a = *reinterpret_cast<const ushort4*>(sp + r * 448);
        const ushort4 d = *reinterpret_cast<const ushort4*>(sp + r * 448 + 4);
        s += bf2f(a.x) + bf2f(a.y) + bf2f(a.z) + bf2f(a.w)
           + bf2f(d.x) + bf2f(d.y) + bf2f(d.z) + bf2f(d.w);
    }
    dst[((size_t)b * GG + g) * 27 + c] = s * (1.f / 64.f);
}

// ---------------- 4a. patch attention S partials via MFMA ----------------
__global__ __launch_bounds__(448, 1)
void k_spart_mfma(const __hip_bfloat16* __restrict__ q, const __hip_bfloat16* __restrict__ k,
                  float* __restrict__ spart) {
    __shared__ ushort lq[MPAD * 64];   // 28672 B
    __shared__ ushort lk[MPAD * 64];
    int blk = blockIdx.x;              // 4b * 54ks = 216
    int ks = blk % NKS;
    int b = blk / NKS;
    const ushort* qb_ = (const ushort*)q + (size_t)b * CHW;
    const ushort* kb_ = (const ushort*)k + (size_t)b * CHW;
    int t = threadIdx.x;
    int w = t >> 6, l = t & 63;
    int lrow = l & 15, lg = l >> 4;    // fragment coords
    int sr = t & 15;                   // d-pair index 0..15 (d = 2sr, 2sr+1)
    int sn8 = t >> 4;                  // col-chunk 0..27 (cols sn8*8..+8)

    f32x4 acc[2][13];
#pragma unroll
    for (int i = 0; i < 2; i++)
#pragma unroll
        for (int ct = 0; ct < 13; ct++) acc[i][ct] = (f32x4){0.f, 0.f, 0.f, 0.f};

    int d0 = ks * KCH;
    for (int step = 0; step < KCH / 32; ++step) {
        int dbase = d0 + step * 32;
        {
            const ushort* s0 = qb_ + (size_t)(dbase + 2 * sr) * NP + sn8 * 8;
            const ushort* s1 = s0 + NP;
            ushort4 a0 = *reinterpret_cast<const ushort4*>(s0);
            ushort4 a1 = *reinterpret_cast<const ushort4*>(s0 + 4);
            ushort4 b0 = *reinterpret_cast<const ushort4*>(s1);
            ushort4 b1 = *reinterpret_cast<const ushort4*>(s1 + 4);
            ushort ra[8] = {a0.x, a0.y, a0.z, a0.w, a1.x, a1.y, a1.z, a1.w};
            ushort rb[8] = {b0.x, b0.y, b0.z, b0.w, b1.x, b1.y, b1.z, b1.w};
#pragma unroll
            for (int kk = 0; kk < 8; kk++) {
                int n = sn8 * 8 + kk;
                uint32_t val = (uint32_t)ra[kk] | ((uint32_t)rb[kk] << 16);
                *reinterpret_cast<uint32_t*>(reinterpret_cast<char*>(lq) + n * ROWB +
                                             ((4 * sr) ^ (16 * (n & 7)))) = val;
            }
        }
        {
            const ushort* s0 = kb_ + (size_t)(dbase + 2 * sr) * NP + sn8 * 8;
            const ushort* s1 = s0 + NP;
            ushort4 a0 = *reinterpret_cast<const ushort4*>(s0);
            ushort4 a1 = *reinterpret_cast<const ushort4*>(s0 + 4);
            ushort4 b0 = *reinterpret_cast<const ushort4*>(s1);
            ushort4 b1 = *reinterpret_cast<const ushort4*>(s1 + 4);
            ushort ra[8] = {a0.x, a0.y, a0.z, a0.w, a1.x, a1.y, a1.z, a1.w};
            ushort rb[8] = {b0.x, b0.y, b0.z, b0.w, b1.x, b1.y, b1.z, b1.w};
#pragma unroll
            for (int kk = 0; kk < 8; kk++) {
                int m = sn8 * 8 + kk;
                uint32_t val = (uint32_t)ra[kk] | ((uint32_t)rb[kk] << 16);
                *reinterpret_cast<uint32_t*>(reinterpret_cast<char*>(lk) + m * ROWB +
                                             ((4 * sr) ^ (16 * (m & 7)))) = val;
            }
        }
        __syncthreads();
        int nA0 = (2 * w) * 16 + lrow;
        int nA1 = nA0 + 16;
        const short8 afr0 = *reinterpret_cast<const short8*>(
            reinterpret_cast<const char*>(lq) + nA0 * ROWB + 16 * (lg ^ (nA0 & 7)));
        const short8 afr1 = *reinterpret_cast<const short8*>(
            reinterpret_cast<const char*>(lq) + nA1 * ROWB + 16 * (lg ^ (nA1 & 7)));
#pragma unroll
        for (int ct = 0; ct < 13; ct++) {
            int m = ct * 16 + lrow;
            const short8 bfr = *reinterpret_cast<const short8*>(
                reinterpret_cast<const char*>(lk) + m * ROWB + 16 * (lg ^ (m & 7)));
            acc[0][ct] = __builtin_amdgcn_mfma_f32_16x16x32_bf16(afr0, bfr, acc[0][ct], 0, 0, 0);
            acc[1][ct] = __builtin_amdgcn_mfma_f32_16x16x32_bf16(afr1, bfr, acc[1][ct], 0, 0, 0);
        }
        __syncthreads();
    }
    float* sp = spart + (size_t)(b * NKS + ks) * NP * MPAD;
#pragma unroll
    for (int i = 0; i < 2; i++) {
        int rt = 2 * w + i;
#pragma unroll
        for (int r = 0; r < 4; r++) {
            int n = rt * 16 + lg * 4 + r;
            if (n < NP) {
#pragma unroll
                for (int ct = 0; ct < 13; ct++)
                    sp[(size_t)n * MPAD + ct * 16 + lrow] = acc[i][ct][r];
            }
        }
    }
}

// ---------------- 4b. reduce + row softmax -> whf fragment-major (step-major) bf16 ----------------
__global__ void k_softmax(const float* __restrict__ spart, __hip_bfloat16* __restrict__ whf) {
    int blk = blockIdx.x;        // BB*196
    int n = blk % NP;            // query row
    int b = blk / NP;
    int m = threadIdx.x;         // key col
    float val = -1e30f;
    if (m < 196) {
        float s = 0.f;
        for (int ks = 0; ks < NKS; ks++)
            s += spart[((size_t)(b * NKS + ks) * NP + n) * MPAD + m];
        val = s * SCALE_P;
    }
    float mx = val;
    for (int o = 32; o; o >>= 1) mx = fmaxf(mx, __shfl_xor(mx, o));
    __shared__ float redm[4], reds[4];
    int wid = threadIdx.x >> 6, lane = threadIdx.x & 63;
    if (lane == 0) redm[wid] = mx;
    __syncthreads();
    mx = fmaxf(fmaxf(redm[0], redm[1]), fmaxf(redm[2], redm[3]));
    float p = (m < 196) ? __expf(val - mx) : 0.f;
    float sm = p;
    for (int o = 32; o; o >>= 1) sm += __shfl_xor(sm, o);
    if (lane == 0) reds[wid] = sm;
    __syncthreads();
    sm = reds[0] + reds[1] + reds[2] + reds[3];
    if (m < 224) {
        int ct = n >> 4, lr = n & 15;
        int step = m >> 5, kg = (m >> 3) & 3, e = m & 7;
        size_t addr = (size_t)b * WFRAG +
                      (((size_t)(step * 13 + ct) * 64 + kg * 16 + lr) << 3) + e;
        whf[addr] = __float2bfloat16((m < 196) ? p / sm : 0.f);
    }
}

// ---------------- 5a. global pooled attention: split-K flash MFMA partials ----------------
// grid = BB * 49 * GKS; each block: 64 queries x 2 chunks (448 keys).
// Unnormalized partial H (27 d) + l (ones-row at d=27) -> pacc [.][q][28].
__global__ __launch_bounds__(256)
void k_gattn_flash(const float* __restrict__ qg, const float* __restrict__ kg,
                   const float* __restrict__ vg, float* __restrict__ pacc) {
    __shared__ __align__(16) ushort ksh[GKC * KST];    // [k][d] 17920 B
    __shared__ __align__(16) ushort vsh[32 * VST];     // [d][k] 14848 B
    __shared__ __align__(16) ushort psh[4][16 * VST];  // per-wave P [q][k] 29696 B

    int blk = blockIdx.x;              // BB * 49 * GKS = 1372
    int ks = blk % GKS;
    int t2 = blk / GKS;
    int b = t2 / 49;
    int q0 = (t2 % 49) * 64;
    int tid = threadIdx.x;
    int w = tid >> 6, l = tid & 63;
    int lr = l & 15, lg = l >> 4;

    for (int i = tid; i < GKC; i += 256) {
        ushort* kr = &ksh[i * KST];
        kr[27] = 0; kr[28] = 0; kr[29] = 0; kr[30] = 0; kr[31] = 0;
        vsh[27 * VST + i] = 0x3f80;    // bf16 1.0
        vsh[28 * VST + i] = 0; vsh[29 * VST + i] = 0;
        vsh[30 * VST + i] = 0; vsh[31 * VST + i] = 0;
    }

    short8 aq;
    {
        const float* qr = qg + ((size_t)b * GG + q0 + w * 16 + lr) * 27;
#pragma unroll
        for (int j = 0; j < 8; j++) {
            int c = 8 * lg + j;
            aq[j] = (c < 27) ? (short)f2bf(qr[c]) : (short)0;
        }
    }

    f32x4 acc_h0 = {0.f, 0.f, 0.f, 0.f};
    f32x4 acc_h1 = {0.f, 0.f, 0.f, 0.f};
    ushort* myps = &psh[w][0];
    const float* kgb = kg + (size_t)b * GG * 27;
    const float* vgb = vg + (size_t)b * GG * 27;

    for (int ch = ks * 2; ch < ks * 2 + 2; ch++) {
        __syncthreads();
        int base = ch * GKC * 27;
        for (int idx = tid; idx < GKC * 27; idx += 256) {
            int kk = idx / 27, c = idx - (idx / 27) * 27;
            ksh[kk * KST + c] = f2bf(kgb[base + idx]);
            vsh[c * VST + kk] = f2bf(vgb[base + idx]);
        }
        __syncthreads();

        f32x4 s[14];
#pragma unroll
        for (int ct = 0; ct < 14; ct++) {
            const short8 bk = *reinterpret_cast<const short8*>(
                &ksh[(ct * 16 + lr) * KST + 8 * lg]);
            s[ct] = __builtin_amdgcn_mfma_f32_16x16x32_bf16(
                aq, bk, (f32x4){0.f, 0.f, 0.f, 0.f}, 0, 0, 0);
        }
#pragma unroll
        for (int ct = 0; ct < 14; ct++) {
#pragma unroll
            for (int r = 0; r < 4; r++) {
                float p = __expf(s[ct][r] * SCALE_G);
                myps[(4 * lg + r) * VST + ct * 16 + lr] = f2bf(p);
            }
        }
#pragma unroll
        for (int kstep = 0; kstep < 7; kstep++) {
            const short8 ap = *reinterpret_cast<const short8*>(
                &myps[lr * VST + kstep * 32 + 8 * lg]);
            const short8 bv0 = *reinterpret_cast<const short8*>(
                &vsh[lr * VST + kstep * 32 + 8 * lg]);
            const short8 bv1 = *reinterpret_cast<const short8*>(
                &vsh[(16 + lr) * VST + kstep * 32 + 8 * lg]);
            acc_h0 = __builtin_amdgcn_mfma_f32_16x16x32_bf16(ap, bv0, acc_h0, 0, 0, 0);
            acc_h1 = __builtin_amdgcn_mfma_f32_16x16x32_bf16(ap, bv1, acc_h1, 0, 0, 0);
        }
    }

    // epilogue: unnormalized partials; d=27 (in acc_h1 col 11) is l
#pragma unroll
    for (int r = 0; r < 4; r++) {
        int q = q0 + w * 16 + 4 * lg + r;
        float* pr = pacc + (((size_t)(b * GKS + ks) * GG + q) * 28);
        pr[lr] = acc_h0[r];
        if (lr < 12) pr[16 + lr] = acc_h1[r];   // d=16..27 incl. l
    }
}

// ---------------- 5b. combine split-K partials ----------------
__global__ void k_gattn_reduce(const float* __restrict__ pacc, float* __restrict__ hg) {
    int t = blockIdx.x * 256 + threadIdx.x;   // < BB*GG*27 = 338688
    if (t >= BB * GG * 27) return;
    int c = t % 27;
    int g = (t / 27) % GG;
    int b = t / (27 * GG);
    float a = 0.f, lsum = 0.f;
#pragma unroll
    for (int ks = 0; ks < GKS; ks++) {
        const float* pr = pacc + (((size_t)(b * GKS + ks) * GG + g) * 28);
        a += pr[c];
        lsum += pr[27];
    }
    hg[((size_t)b * GG + g) * 27 + c] = a / lsum;
}

// ---------------- 6. h_patch GEMM via MFMA + bf16-LDS coalesced epilogue ----------------
__global__ __launch_bounds__(256)
void k_hp_fused(const __hip_bfloat16* __restrict__ v, const __hip_bfloat16* __restrict__ whf,
                const float* __restrict__ x, const float* __restrict__ hg,
                float* __restrict__ out) {
    __shared__ __align__(16) ushort hbuf[64 * HST];   // 26112 B
    int nper = gridDim.x >> 3;         // 216
    int bid = blockIdx.x;
    int blk = (bid & 7) * nper + (bid >> 3);   // bijective XCD swizzle
    int b = blk / 432;
    int grp = blk % 432;
    int tid = threadIdx.x;
    int w = tid >> 6, l = tid & 63;
    int ar = l & 15;                   // A row within tile / B col
    int kg = l >> 4;                   // k-group
    int D0 = (grp * 4 + w) * 16;       // d-tile base

    // ---- early x prefetch (epilogue operand) ----
    int c = grp >> 4;                      // (grp*64) >> 10
    int pix0 = (grp & 15) * 64 * NP;       // strip_base * 196
    const float* xb = x + (size_t)b * CHW + (size_t)c * HW + pix0;
    float4 xpre[12];
#pragma unroll
    for (int it = 0; it < 12; ++it)
        xpre[it] = *reinterpret_cast<const float4*>(&xb[(tid + it * 256) * 4]);

    const ushort* vb = (const ushort*)v + (size_t)b * CHW;
    const ushort* wf = (const ushort*)whf + (size_t)b * WFRAG;

    const ushort* arow = vb + (size_t)(D0 + ar) * NP;
    short8 av[7];
#pragma unroll
    for (int step = 0; step < 7; ++step) {
        int joff = step * 32 + kg * 8;
        ushort4 alo = *reinterpret_cast<const ushort4*>(arow + joff);
        ushort4 ahi = *reinterpret_cast<const ushort4*>(arow + joff + 4);
        av[step][0] = alo.x; av[step][1] = alo.y; av[step][2] = alo.z; av[step][3] = alo.w;
        av[step][4] = ahi.x; av[step][5] = ahi.y; av[step][6] = ahi.z; av[step][7] = ahi.w;
    }

    f32x4 acc[13];
#pragma unroll
    for (int ct = 0; ct < 13; ct++) acc[ct] = (f32x4){0.f, 0.f, 0.f, 0.f};

#pragma unroll
    for (int step = 0; step < 7; ++step) {
        short8 bv[13];
#pragma unroll
        for (int ct = 0; ct < 13; ct++)
            bv[ct] = *reinterpret_cast<const short8*>(
                wf + (((size_t)(step * 13 + ct) * 64 + l) << 3));
#pragma unroll
        for (int ct = 0; ct < 13; ct++)
            acc[ct] = __builtin_amdgcn_mfma_f32_16x16x32_bf16(av[step], bv[ct], acc[ct], 0, 0, 0);
    }

#pragma unroll
    for (int ct = 0; ct < 13; ct++) {
        int i = ct * 16 + ar;
        if (i < NP) {
#pragma unroll
            for (int r = 0; r < 4; r++)
                hbuf[(w * 16 + kg * 4 + r) * HST + i] = f2bf(acc[ct][r]);
        }
    }
    __syncthreads();

    float* ob = out + (size_t)b * CHW + (size_t)c * HW + pix0;
    const float* hgb = hg + (size_t)b * GG * 27;
#pragma unroll
    for (int it = 0; it < 12; ++it) {
        int idx4 = tid + it * 256;
        int j = idx4 * 4;
        int sl = j / NP;
        int i = j - sl * NP;
        ushort4 hv = *reinterpret_cast<const ushort4*>(&hbuf[sl * HST + i]);
        int pix = pix0 + j;
        int h = pix / 448;
        int w2 = pix - h * 448;
        int g = (h >> 3) * 56 + (w2 >> 3);
        float hgs = 0.25f * hgb[g * 27 + c];
        float4 xv = xpre[it];
        float4 ov;
        ov.x = xv.x + 0.75f * bf2f(hv.x) + hgs;
        ov.y = xv.y + 0.75f * bf2f(hv.y) + hgs;
        ov.z = xv.z + 0.75f * bf2f(hv.z) + hgs;
        ov.w = xv.w + 0.75f * bf2f(hv.w) + hgs;
        *reinterpret_cast<float4*>(&ob[j]) = ov;
    }
    if (tid < 64) {
        int idx4 = 3072 + tid;
        int j = idx4 * 4;
        int sl = j / NP;
        int i = j - sl * NP;
        ushort4 hv = *reinterpret_cast<const ushort4*>(&hbuf[sl * HST + i]);
        int pix = pix0 + j;
        int h = pix / 448;
        int w2 = pix - h * 448;
        int g = (h >> 3) * 56 + (w2 >> 3);
        float hgs = 0.25f * hgb[g * 27 + c];
        float4 xv = *reinterpret_cast<const float4*>(&xb[j]);
        float4 ov;
        ov.x = xv.x + 0.75f * bf2f(hv.x) + hgs;
        ov.y = xv.y + 0.75f * bf2f(hv.y) + hgs;
        ov.z = xv.z + 0.75f * bf2f(hv.z) + hgs;
        ov.w = xv.w + 0.75f * bf2f(hv.w) + hgs;
        *reinterpret_cast<float4*>(&ob[j]) = ov;
    }
}

// ---------------- launch ----------------
extern "C" void kernel_launch(void* const* d_in, const int* in_sizes, int n_in,
                              void* d_out, int out_size, void* d_ws, size_t ws_size,
                              hipStream_t stream) {
    const float* x    = (const float*)d_in[0];
    const float* gnw  = (const float*)d_in[1];
    const float* gnb  = (const float*)d_in[2];
    const float* qw   = (const float*)d_in[3];
    const float* qb   = (const float*)d_in[4];
    const float* kw   = (const float*)d_in[5];
    const float* kb   = (const float*)d_in[6];
    const float* vw   = (const float*)d_in[7];
    const float* vb   = (const float*)d_in[8];
    const float* pjw  = (const float*)d_in[9];
    float* out = (float*)d_out;

    char* ws = (char*)d_ws;
    size_t off = 0;
    auto alloc = [&](size_t bytes) { void* p = ws + off; off += (bytes + 255) & ~(size_t)255; return p; };
    // qkv: contiguous [3][BB][27][HW] bf16 + 64B zero tail (k_hp_fused overread)
    __hip_bfloat16* qkvbuf = (__hip_bfloat16*)alloc((size_t)3 * BB * CHW * 2 + 64);
    __hip_bfloat16* qbf = qkvbuf;
    __hip_bfloat16* kbf = qkvbuf + (size_t)BB * CHW;
    __hip_bfloat16* vbf = qkvbuf + (size_t)2 * BB * CHW;
    // spart (37.9MB, dead after k_softmax) aliases gattn pacc (BB*GKS*GG*28 f32 = 9.8MB)
    float* spart = (float*)alloc((size_t)BB * NKS * NP * MPAD * 4);
    float* pacc  = spart;
    __hip_bfloat16* wHat = (__hip_bfloat16*)alloc((size_t)BB * WFRAG * 2);
    float* qg    = (float*)alloc((size_t)BB * GG * 27 * 4);
    float* kg    = (float*)alloc((size_t)BB * GG * 27 * 4);
    float* vg    = (float*)alloc((size_t)BB * GG * 27 * 4);
    float* hg    = (float*)alloc((size_t)BB * GG * 27 * 4);
    float* part  = (float*)alloc((size_t)BB * 1024 * 2 * 4);
    float* stats = (float*)alloc((size_t)BB * 2 * 4);
    float* pvw   = (float*)alloc(729 * 4);
    float* pvb   = (float*)alloc(27 * 4);

    (void)hipMemsetAsync((char*)qkvbuf + (size_t)3 * BB * CHW * 2, 0, 64, stream);
    k_fold<<<1, 256, 0, stream>>>(pjw, vw, vb, pvw, pvb);
    k_gn_partial<<<BB * 1024, 256, 0, stream>>>(x, part);
    k_gn_final<<<BB, 256, 0, stream>>>(part, stats);
    k_qkv_mfma<<<(BB * HW) / 256, 256, 0, stream>>>(x, stats, qw, qb, kw, kb, pvw, pvb,
                                                    gnw, gnb, qkvbuf);
    k_pool<<<(BB * 27 * GG) / 256, 256, 0, stream>>>(qbf, qg);
    k_pool<<<(BB * 27 * GG) / 256, 256, 0, stream>>>(kbf, kg);
    k_pool<<<(BB * 27 * GG) / 256, 256, 0, stream>>>(vbf, vg);
    k_spart_mfma<<<BB * NKS, 448, 0, stream>>>(qbf, kbf, spart);
    k_softmax<<<BB * NP, 256, 0, stream>>>(spart, wHat);
    k_gattn_flash<<<BB * 49 * GKS, 256, 0, stream>>>(qg, kg, vg, pacc);
    k_gattn_reduce<<<(BB * GG * 27 + 255) / 256, 256, 0, stream>>>(pacc, hg);
    k_hp_fused<<<BB * 432, 256, 0, stream>>>(vbf, wHat, x, hg, out);
}

// Round 19
// 255.595 us; speedup vs baseline: 1.1730x; 1.0018x over previous
//
#include <hip/hip_runtime.h>
#include <hip/hip_bf16.h>
#include <cstdint>

// ---------------- problem constants ----------------
namespace {
constexpr int BB = 4;
constexpr int CC = 27;
constexpr int HW = 448 * 448;                 // 200704
constexpr long long CHW = (long long)CC * HW; // 5419008
constexpr int NP = 196;                        // patch positions
constexpr int GG = 56 * 56;                    // 3136 pooled positions
constexpr int DTOT = CC * 1024;                // 27648
constexpr float SCALE_P = 0.0060140449f;       // 1/sqrt(27648)
constexpr float SCALE_G = 0.1924500897f;       // 1/sqrt(27)
constexpr float EPSV = 1e-5f;
// MFMA spart config
constexpr int KCH = 512;                       // d-chunk per block
constexpr int NKS = DTOT / KCH;                // 54 partials
constexpr int MPAD = 224;                      // padded n/m (14 tiles of 16)
constexpr int ROWB = 128;                      // LDS bytes per row
// wHat fragment-major, step-major: [7 step][13 ct][64 lane][8 elem] bf16 = 46592 elems
constexpr int WFRAG = 7 * 13 * 64 * 8;
// qkv-MFMA config
constexpr int XST = 40;                        // LDS row stride (shorts)
// flash gattn config
constexpr int GKC = 224;                       // keys per chunk (14 chunks)
constexpr int GKS = 14;                        // key splits (1 chunk per block)
constexpr int KST = 40;                        // ks row stride (shorts)
constexpr int VST = 232;                       // vs/ps row stride (shorts)
// hp epilogue LDS stride (shorts, bf16)
constexpr int HST = 204;
}

typedef __attribute__((ext_vector_type(8))) short short8;
typedef __attribute__((ext_vector_type(4))) float f32x4;

__device__ __forceinline__ float bf2f(unsigned short u) {
    return __uint_as_float(((uint32_t)u) << 16);
}

__device__ __forceinline__ ushort f2bf(float f) {
    union { __hip_bfloat16 h; ushort u; } cv;
    cv.h = __float2bfloat16(f);
    return cv.u;
}

// ---------------- 0. fold proj into V weights: pvw = proj*vw, pvb = proj*vb ----------------
__global__ void k_fold(const float* __restrict__ pjw, const float* __restrict__ vw,
                       const float* __restrict__ vb, float* __restrict__ pvw,
                       float* __restrict__ pvb) {
    __shared__ float pj[729], vv[729], vbs[27];
    int t = threadIdx.x;
    for (int i = t; i < 729; i += 256) { pj[i] = pjw[i]; vv[i] = vw[i]; }
    if (t < 27) vbs[t] = vb[t];
    __syncthreads();
    for (int i = t; i < 729; i += 256) {
        int o = i / 27, c2 = i - (i / 27) * 27;
        float s = 0.f;
#pragma unroll
        for (int c = 0; c < 27; c++) s += pj[o * 27 + c] * vv[c * 27 + c2];
        pvw[i] = s;
    }
    if (t < 27) {
        float s = 0.f;
#pragma unroll
        for (int c = 0; c < 27; c++) s += pj[t * 27 + c] * vbs[c];
        pvb[t] = s;
    }
}

// ---------------- 1. GroupNorm stats ----------------
__global__ void k_gn_partial(const float* __restrict__ x, float* __restrict__ part) {
    int blk = blockIdx.x;          // BB*1024 blocks
    int b = blk >> 10;
    int chunk = blk & 1023;
    const int CLEN = (int)(CHW / 1024);   // 5292
    const float* p = x + (size_t)b * CHW + (size_t)chunk * CLEN;
    float s = 0.f, ss = 0.f;
    for (int i = threadIdx.x; i < CLEN; i += 256) {
        float v = p[i];
        s += v; ss += v * v;
    }
    for (int o = 32; o; o >>= 1) { s += __shfl_down(s, o); ss += __shfl_down(ss, o); }
    __shared__ float ls[4], lss[4];
    int wid = threadIdx.x >> 6, lane = threadIdx.x & 63;
    if (lane == 0) { ls[wid] = s; lss[wid] = ss; }
    __syncthreads();
    if (threadIdx.x == 0) {
        float S = ls[0] + ls[1] + ls[2] + ls[3];
        float SS = lss[0] + lss[1] + lss[2] + lss[3];
        part[blk * 2] = S; part[blk * 2 + 1] = SS;
    }
}

__global__ void k_gn_final(const float* __restrict__ part, float* __restrict__ stats) {
    int b = blockIdx.x;
    float s = 0.f, ss = 0.f;
    for (int i = threadIdx.x; i < 1024; i += 256) {
        s += part[(b * 1024 + i) * 2];
        ss += part[(b * 1024 + i) * 2 + 1];
    }
    for (int o = 32; o; o >>= 1) { s += __shfl_down(s, o); ss += __shfl_down(ss, o); }
    __shared__ float ls[4], lss[4];
    int wid = threadIdx.x >> 6, lane = threadIdx.x & 63;
    if (lane == 0) { ls[wid] = s; lss[wid] = ss; }
    __syncthreads();
    if (threadIdx.x == 0) {
        float S = ls[0] + ls[1] + ls[2] + ls[3];
        float SS = lss[0] + lss[1] + lss[2] + lss[3];
        float mean = S / (float)CHW;
        float var = SS / (float)CHW - mean * mean;
        stats[b * 2] = mean;
        stats[b * 2 + 1] = rsqrtf(var + EPSV);
    }
}

// ---------------- 2. GN-apply + QKV conv1x1 via MFMA (-> bf16) ----------------
__global__ __launch_bounds__(256, 2)
void k_qkv_mfma(const float* __restrict__ x, const float* __restrict__ stats,
                const float* __restrict__ qw, const float* __restrict__ qb,
                const float* __restrict__ kw, const float* __restrict__ kb,
                const float* __restrict__ vw, const float* __restrict__ vb,
                const float* __restrict__ gnw, const float* __restrict__ gnb,
                __hip_bfloat16* __restrict__ qkv) {
    __shared__ ushort xs[256 * XST];            // 20480 B
    __shared__ ushort wls[96 * XST];            // 7680 B
    __shared__ __align__(16) float bls[96];
    __shared__ float gwls[27], gbls[27];

    int tid = threadIdx.x;
    int P0 = blockIdx.x * 256;                  // global pixel base
    int b = P0 / HW;                            // HW % 256 == 0: no straddle
    int hw0 = P0 - b * HW;

    for (int i = tid; i < 96 * 32; i += 256) {
        int row = i >> 5, c = i & 31;
        float wv = 0.f;
        if (c < 27 && row < 81) {
            int t = (row >= 54) ? 2 : (row >= 27 ? 1 : 0);
            int oc = row - t * 27;
            const float* wp = (t == 0) ? qw : (t == 1) ? kw : vw;
            wv = wp[oc * 27 + c];
        }
        wls[row * XST + c] = f2bf(wv);
    }
    if (tid < 96) {
        float bv = 0.f;
        if (tid < 27) bv = qb[tid];
        else if (tid < 54) bv = kb[tid - 27];
        else if (tid < 81) bv = vb[tid - 54];
        bls[tid] = bv;
    }
    if (tid < 27) { gwls[tid] = gnw[tid]; gbls[tid] = gnb[tid]; }
    float mean = stats[b * 2], rstd = stats[b * 2 + 1];
    __syncthreads();

    {
        const float* xp = x + (size_t)b * CHW + hw0 + tid;
        ushort xv[28];
#pragma unroll
        for (int c = 0; c < 27; c++) {
            float v = (xp[(size_t)c * HW] - mean) * rstd * gwls[c] + gbls[c];
            xv[c] = f2bf(v);
        }
        xv[27] = 0;
        uint32_t* xrow = reinterpret_cast<uint32_t*>(&xs[tid * XST]);
#pragma unroll
        for (int i = 0; i < 14; i++)
            xrow[i] = (uint32_t)xv[2 * i] | ((uint32_t)xv[2 * i + 1] << 16);
        xrow[14] = 0; xrow[15] = 0;
    }
    __syncthreads();

    int w = tid >> 6, l = tid & 63;
    int lrow = l & 15, kg = l >> 4;

    short8 afr[6];
    f32x4 binit[6];
#pragma unroll
    for (int mt = 0; mt < 6; mt++) {
        afr[mt] = *reinterpret_cast<const short8*>(&wls[(mt * 16 + lrow) * XST + kg * 8]);
        binit[mt] = *reinterpret_cast<const f32x4*>(&bls[mt * 16 + kg * 4]);
    }

    f32x4 acc[4][6];
#pragma unroll
    for (int pt = 0; pt < 4; pt++) {
        const short8 bfr = *reinterpret_cast<const short8*>(
            &xs[(w * 64 + pt * 16 + lrow) * XST + kg * 8]);
#pragma unroll
        for (int mt = 0; mt < 6; mt++)
            acc[pt][mt] = __builtin_amdgcn_mfma_f32_16x16x32_bf16(afr[mt], bfr, binit[mt], 0, 0, 0);
    }

    ushort* ob = (ushort*)qkv;
#pragma unroll
    for (int pt = 0; pt < 4; pt++) {
        int hw = hw0 + w * 64 + pt * 16 + lrow;
#pragma unroll
        for (int mt = 0; mt < 6; mt++) {
#pragma unroll
            for (int r = 0; r < 4; r++) {
                int o = mt * 16 + kg * 4 + r;
                if (o < 81) {
                    int t = (o >= 54) ? 2 : (o >= 27 ? 1 : 0);
                    int oc = o - t * 27;
                    ob[((size_t)t * BB + b) * CHW + (size_t)oc * HW + hw] = f2bf(acc[pt][mt][r]);
                }
            }
        }
    }
}

// ---------------- 3. 8x8 avg pool -> transposed [b][g][27] ----------------
__global__ void k_pool(const __hip_bfloat16* __restrict__ src, float* __restrict__ dst) {
    int idx = blockIdx.x * 256 + threadIdx.x;  // < 4*27*3136 = 338688
    int g = idx % GG;
    int t = idx / GG;
    int c = t % 27;
    int b = t / 27;
    int gh = g / 56, gw = g - (g / 56) * 56;
    const ushort* sp = (const ushort*)src + (size_t)(b * 27 + c) * HW + (size_t)(gh * 8) * 448 + gw * 8;
    float s = 0.f;
#pragma unroll
    for (int r = 0; r < 8; r++) {
        const ushort4 a = *reinterpret_cast<const ushort4*>(sp + r * 448);
        const ushort4 d = *reinterpret_cast<const ushort4*>(sp + r * 448 + 4);
        s += bf2f(a.x) + bf2f(a.y) + bf2f(a.z) + bf2f(a.w)
           + bf2f(d.x) + bf2f(d.y) + bf2f(d.z) + bf2f(d.w);
    }
    dst[((size_t)b * GG + g) * 27 + c] = s * (1.f / 64.f);
}

// ---------------- 4a. patch attention S partials via MFMA ----------------
__global__ __launch_bounds__(448, 1)
void k_spart_mfma(const __hip_bfloat16* __restrict__ q, const __hip_bfloat16* __restrict__ k,
                  float* __restrict__ spart) {
    __shared__ ushort lq[MPAD * 64];   // 28672 B
    __shared__ ushort lk[MPAD * 64];
    int blk = blockIdx.x;              // 4b * 54ks = 216
    int ks = blk % NKS;
    int b = blk / NKS;
    const ushort* qb_ = (const ushort*)q + (size_t)b * CHW;
    const ushort* kb_ = (const ushort*)k + (size_t)b * CHW;
    int t = threadIdx.x;
    int w = t >> 6, l = t & 63;
    int lrow = l & 15, lg = l >> 4;    // fragment coords
    int sr = t & 15;                   // d-pair index 0..15 (d = 2sr, 2sr+1)
    int sn8 = t >> 4;                  // col-chunk 0..27 (cols sn8*8..+8)

    f32x4 acc[2][13];
#pragma unroll
    for (int i = 0; i < 2; i++)
#pragma unroll
        for (int ct = 0; ct < 13; ct++) acc[i][ct] = (f32x4){0.f, 0.f, 0.f, 0.f};

    int d0 = ks * KCH;
    for (int step = 0; step < KCH / 32; ++step) {
        int dbase = d0 + step * 32;
        {
            const ushort* s0 = qb_ + (size_t)(dbase + 2 * sr) * NP + sn8 * 8;
            const ushort* s1 = s0 + NP;
            ushort4 a0 = *reinterpret_cast<const ushort4*>(s0);
            ushort4 a1 = *reinterpret_cast<const ushort4*>(s0 + 4);
            ushort4 b0 = *reinterpret_cast<const ushort4*>(s1);
            ushort4 b1 = *reinterpret_cast<const ushort4*>(s1 + 4);
            ushort ra[8] = {a0.x, a0.y, a0.z, a0.w, a1.x, a1.y, a1.z, a1.w};
            ushort rb[8] = {b0.x, b0.y, b0.z, b0.w, b1.x, b1.y, b1.z, b1.w};
#pragma unroll
            for (int kk = 0; kk < 8; kk++) {
                int n = sn8 * 8 + kk;
                uint32_t val = (uint32_t)ra[kk] | ((uint32_t)rb[kk] << 16);
                *reinterpret_cast<uint32_t*>(reinterpret_cast<char*>(lq) + n * ROWB +
                                             ((4 * sr) ^ (16 * (n & 7)))) = val;
            }
        }
        {
            const ushort* s0 = kb_ + (size_t)(dbase + 2 * sr) * NP + sn8 * 8;
            const ushort* s1 = s0 + NP;
            ushort4 a0 = *reinterpret_cast<const ushort4*>(s0);
            ushort4 a1 = *reinterpret_cast<const ushort4*>(s0 + 4);
            ushort4 b0 = *reinterpret_cast<const ushort4*>(s1);
            ushort4 b1 = *reinterpret_cast<const ushort4*>(s1 + 4);
            ushort ra[8] = {a0.x, a0.y, a0.z, a0.w, a1.x, a1.y, a1.z, a1.w};
            ushort rb[8] = {b0.x, b0.y, b0.z, b0.w, b1.x, b1.y, b1.z, b1.w};
#pragma unroll
            for (int kk = 0; kk < 8; kk++) {
                int m = sn8 * 8 + kk;
                uint32_t val = (uint32_t)ra[kk] | ((uint32_t)rb[kk] << 16);
                *reinterpret_cast<uint32_t*>(reinterpret_cast<char*>(lk) + m * ROWB +
                                             ((4 * sr) ^ (16 * (m & 7)))) = val;
            }
        }
        __syncthreads();
        int nA0 = (2 * w) * 16 + lrow;
        int nA1 = nA0 + 16;
        const short8 afr0 = *reinterpret_cast<const short8*>(
            reinterpret_cast<const char*>(lq) + nA0 * ROWB + 16 * (lg ^ (nA0 & 7)));
        const short8 afr1 = *reinterpret_cast<const short8*>(
            reinterpret_cast<const char*>(lq) + nA1 * ROWB + 16 * (lg ^ (nA1 & 7)));
#pragma unroll
        for (int ct = 0; ct < 13; ct++) {
            int m = ct * 16 + lrow;
            const short8 bfr = *reinterpret_cast<const short8*>(
                reinterpret_cast<const char*>(lk) + m * ROWB + 16 * (lg ^ (m & 7)));
            acc[0][ct] = __builtin_amdgcn_mfma_f32_16x16x32_bf16(afr0, bfr, acc[0][ct], 0, 0, 0);
            acc[1][ct] = __builtin_amdgcn_mfma_f32_16x16x32_bf16(afr1, bfr, acc[1][ct], 0, 0, 0);
        }
        __syncthreads();
    }
    float* sp = spart + (size_t)(b * NKS + ks) * NP * MPAD;
#pragma unroll
    for (int i = 0; i < 2; i++) {
        int rt = 2 * w + i;
#pragma unroll
        for (int r = 0; r < 4; r++) {
            int n = rt * 16 + lg * 4 + r;
            if (n < NP) {
#pragma unroll
                for (int ct = 0; ct < 13; ct++)
                    sp[(size_t)n * MPAD + ct * 16 + lrow] = acc[i][ct][r];
            }
        }
    }
}

// ---------------- 4b. reduce + row softmax -> whf fragment-major (step-major) bf16 ----------------
__global__ void k_softmax(const float* __restrict__ spart, __hip_bfloat16* __restrict__ whf) {
    int blk = blockIdx.x;        // BB*196
    int n = blk % NP;            // query row
    int b = blk / NP;
    int m = threadIdx.x;         // key col
    float val = -1e30f;
    if (m < 196) {
        float s = 0.f;
        for (int ks = 0; ks < NKS; ks++)
            s += spart[((size_t)(b * NKS + ks) * NP + n) * MPAD + m];
        val = s * SCALE_P;
    }
    float mx = val;
    for (int o = 32; o; o >>= 1) mx = fmaxf(mx, __shfl_xor(mx, o));
    __shared__ float redm[4], reds[4];
    int wid = threadIdx.x >> 6, lane = threadIdx.x & 63;
    if (lane == 0) redm[wid] = mx;
    __syncthreads();
    mx = fmaxf(fmaxf(redm[0], redm[1]), fmaxf(redm[2], redm[3]));
    float p = (m < 196) ? __expf(val - mx) : 0.f;
    float sm = p;
    for (int o = 32; o; o >>= 1) sm += __shfl_xor(sm, o);
    if (lane == 0) reds[wid] = sm;
    __syncthreads();
    sm = reds[0] + reds[1] + reds[2] + reds[3];
    if (m < 224) {
        int ct = n >> 4, lr = n & 15;
        int step = m >> 5, kg = (m >> 3) & 3, e = m & 7;
        size_t addr = (size_t)b * WFRAG +
                      (((size_t)(step * 13 + ct) * 64 + kg * 16 + lr) << 3) + e;
        whf[addr] = __float2bfloat16((m < 196) ? p / sm : 0.f);
    }
}

// ---------------- 5a. global pooled attention: split-K flash MFMA partials ----------------
// grid = BB * 49 * GKS (GKS=14, 1 chunk of 224 keys per block).
// Unnormalized partial H (27 d) + l (ones-row at d=27) -> pacc [.][q][28].
__global__ __launch_bounds__(256)
void k_gattn_flash(const float* __restrict__ qg, const float* __restrict__ kg,
                   const float* __restrict__ vg, float* __restrict__ pacc) {
    __shared__ __align__(16) ushort ksh[GKC * KST];    // [k][d] 17920 B
    __shared__ __align__(16) ushort vsh[32 * VST];     // [d][k] 14848 B
    __shared__ __align__(16) ushort psh[4][16 * VST];  // per-wave P [q][k] 29696 B

    int blk = blockIdx.x;              // BB * 49 * GKS = 2744
    int ks = blk % GKS;
    int t2 = blk / GKS;
    int b = t2 / 49;
    int q0 = (t2 % 49) * 64;
    int tid = threadIdx.x;
    int w = tid >> 6, l = tid & 63;
    int lr = l & 15, lg = l >> 4;

    for (int i = tid; i < GKC; i += 256) {
        ushort* kr = &ksh[i * KST];
        kr[27] = 0; kr[28] = 0; kr[29] = 0; kr[30] = 0; kr[31] = 0;
        vsh[27 * VST + i] = 0x3f80;    // bf16 1.0
        vsh[28 * VST + i] = 0; vsh[29 * VST + i] = 0;
        vsh[30 * VST + i] = 0; vsh[31 * VST + i] = 0;
    }

    short8 aq;
    {
        const float* qr = qg + ((size_t)b * GG + q0 + w * 16 + lr) * 27;
#pragma unroll
        for (int j = 0; j < 8; j++) {
            int c = 8 * lg + j;
            aq[j] = (c < 27) ? (short)f2bf(qr[c]) : (short)0;
        }
    }

    f32x4 acc_h0 = {0.f, 0.f, 0.f, 0.f};
    f32x4 acc_h1 = {0.f, 0.f, 0.f, 0.f};
    ushort* myps = &psh[w][0];
    const float* kgb = kg + (size_t)b * GG * 27;
    const float* vgb = vg + (size_t)b * GG * 27;

    {
        int ch = ks;
        int base = ch * GKC * 27;
        for (int idx = tid; idx < GKC * 27; idx += 256) {
            int kk = idx / 27, c = idx - (idx / 27) * 27;
            ksh[kk * KST + c] = f2bf(kgb[base + idx]);
            vsh[c * VST + kk] = f2bf(vgb[base + idx]);
        }
        __syncthreads();

        f32x4 s[14];
#pragma unroll
        for (int ct = 0; ct < 14; ct++) {
            const short8 bk = *reinterpret_cast<const short8*>(
                &ksh[(ct * 16 + lr) * KST + 8 * lg]);
            s[ct] = __builtin_amdgcn_mfma_f32_16x16x32_bf16(
                aq, bk, (f32x4){0.f, 0.f, 0.f, 0.f}, 0, 0, 0);
        }
#pragma unroll
        for (int ct = 0; ct < 14; ct++) {
#pragma unroll
            for (int r = 0; r < 4; r++) {
                float p = __expf(s[ct][r] * SCALE_G);
                myps[(4 * lg + r) * VST + ct * 16 + lr] = f2bf(p);
            }
        }
#pragma unroll
        for (int kstep = 0; kstep < 7; kstep++) {
            const short8 ap = *reinterpret_cast<const short8*>(
                &myps[lr * VST + kstep * 32 + 8 * lg]);
            const short8 bv0 = *reinterpret_cast<const short8*>(
                &vsh[lr * VST + kstep * 32 + 8 * lg]);
            const short8 bv1 = *reinterpret_cast<const short8*>(
                &vsh[(16 + lr) * VST + kstep * 32 + 8 * lg]);
            acc_h0 = __builtin_amdgcn_mfma_f32_16x16x32_bf16(ap, bv0, acc_h0, 0, 0, 0);
            acc_h1 = __builtin_amdgcn_mfma_f32_16x16x32_bf16(ap, bv1, acc_h1, 0, 0, 0);
        }
    }

    // epilogue: unnormalized partials; d=27 (in acc_h1 col 11) is l
#pragma unroll
    for (int r = 0; r < 4; r++) {
        int q = q0 + w * 16 + 4 * lg + r;
        float* pr = pacc + (((size_t)(b * GKS + ks) * GG + q) * 28);
        pr[lr] = acc_h0[r];
        if (lr < 12) pr[16 + lr] = acc_h1[r];   // d=16..27 incl. l
    }
}

// ---------------- 5b. combine split-K partials -> hg TRANSPOSED [b][27][GG] ----------------
__global__ void k_gattn_reduce(const float* __restrict__ pacc, float* __restrict__ hg) {
    int t = blockIdx.x * 256 + threadIdx.x;   // < BB*GG*27 = 338688
    if (t >= BB * GG * 27) return;
    int c = t % 27;
    int g = (t / 27) % GG;
    int b = t / (27 * GG);
    float a = 0.f, lsum = 0.f;
#pragma unroll
    for (int ks = 0; ks < GKS; ks++) {
        const float* pr = pacc + (((size_t)(b * GKS + ks) * GG + g) * 28);
        a += pr[c];
        lsum += pr[27];
    }
    hg[((size_t)b * 27 + c) * GG + g] = a / lsum;
}

// ---------------- 6. h_patch GEMM via MFMA + bf16-LDS coalesced epilogue ----------------
// hg is transposed [b][27][GG]: epilogue gather is 32 consecutive floats per wave.
// sched_barrier(0) pins the x prefetch issue before the MFMA phase (T14).
__global__ __launch_bounds__(256)
void k_hp_fused(const __hip_bfloat16* __restrict__ v, const __hip_bfloat16* __restrict__ whf,
                const float* __restrict__ x, const float* __restrict__ hg,
                float* __restrict__ out) {
    __shared__ __align__(16) ushort hbuf[64 * HST];   // 26112 B
    int nper = gridDim.x >> 3;         // 216
    int bid = blockIdx.x;
    int blk = (bid & 7) * nper + (bid >> 3);   // bijective XCD swizzle
    int b = blk / 432;
    int grp = blk % 432;
    int tid = threadIdx.x;
    int w = tid >> 6, l = tid & 63;
    int ar = l & 15;                   // A row within tile / B col
    int kg = l >> 4;                   // k-group
    int D0 = (grp * 4 + w) * 16;       // d-tile base

    // ---- early x prefetch (epilogue operand) ----
    int c = grp >> 4;                      // (grp*64) >> 10
    int pix0 = (grp & 15) * 64 * NP;       // strip_base * 196
    const float* xb = x + (size_t)b * CHW + (size_t)c * HW + pix0;
    float4 xpre[12];
#pragma unroll
    for (int it = 0; it < 12; ++it)
        xpre[it] = *reinterpret_cast<const float4*>(&xb[(tid + it * 256) * 4]);
    __builtin_amdgcn_sched_barrier(0);     // pin load issue here (waitcnt stays at use)

    const ushort* vb = (const ushort*)v + (size_t)b * CHW;
    const ushort* wf = (const ushort*)whf + (size_t)b * WFRAG;

    const ushort* arow = vb + (size_t)(D0 + ar) * NP;
    short8 av[7];
#pragma unroll
    for (int step = 0; step < 7; ++step) {
        int joff = step * 32 + kg * 8;
        ushort4 alo = *reinterpret_cast<const ushort4*>(arow + joff);
        ushort4 ahi = *reinterpret_cast<const ushort4*>(arow + joff + 4);
        av[step][0] = alo.x; av[step][1] = alo.y; av[step][2] = alo.z; av[step][3] = alo.w;
        av[step][4] = ahi.x; av[step][5] = ahi.y; av[step][6] = ahi.z; av[step][7] = ahi.w;
    }

    f32x4 acc[13];
#pragma unroll
    for (int ct = 0; ct < 13; ct++) acc[ct] = (f32x4){0.f, 0.f, 0.f, 0.f};

#pragma unroll
    for (int step = 0; step < 7; ++step) {
        short8 bv[13];
#pragma unroll
        for (int ct = 0; ct < 13; ct++)
            bv[ct] = *reinterpret_cast<const short8*>(
                wf + (((size_t)(step * 13 + ct) * 64 + l) << 3));
#pragma unroll
        for (int ct = 0; ct < 13; ct++)
            acc[ct] = __builtin_amdgcn_mfma_f32_16x16x32_bf16(av[step], bv[ct], acc[ct], 0, 0, 0);
    }

#pragma unroll
    for (int ct = 0; ct < 13; ct++) {
        int i = ct * 16 + ar;
        if (i < NP) {
#pragma unroll
            for (int r = 0; r < 4; r++)
                hbuf[(w * 16 + kg * 4 + r) * HST + i] = f2bf(acc[ct][r]);
        }
    }
    __syncthreads();

    float* ob = out + (size_t)b * CHW + (size_t)c * HW + pix0;
    const float* hgc = hg + ((size_t)b * 27 + c) * GG;   // transposed row for channel c
#pragma unroll
    for (int it = 0; it < 12; ++it) {
        int idx4 = tid + it * 256;
        int j = idx4 * 4;
        int sl = j / NP;
        int i = j - sl * NP;
        ushort4 hv = *reinterpret_cast<const ushort4*>(&hbuf[sl * HST + i]);
        int pix = pix0 + j;
        int h = pix / 448;
        int w2 = pix - h * 448;
        int g = (h >> 3) * 56 + (w2 >> 3);
        float hgs = 0.25f * hgc[g];
        float4 xv = xpre[it];
        float4 ov;
        ov.x = xv.x + 0.75f * bf2f(hv.x) + hgs;
        ov.y = xv.y + 0.75f * bf2f(hv.y) + hgs;
        ov.z = xv.z + 0.75f * bf2f(hv.z) + hgs;
        ov.w = xv.w + 0.75f * bf2f(hv.w) + hgs;
        *reinterpret_cast<float4*>(&ob[j]) = ov;
    }
    if (tid < 64) {
        int idx4 = 3072 + tid;
        int j = idx4 * 4;
        int sl = j / NP;
        int i = j - sl * NP;
        ushort4 hv = *reinterpret_cast<const ushort4*>(&hbuf[sl * HST + i]);
        int pix = pix0 + j;
        int h = pix / 448;
        int w2 = pix - h * 448;
        int g = (h >> 3) * 56 + (w2 >> 3);
        float hgs = 0.25f * hgc[g];
        float4 xv = *reinterpret_cast<const float4*>(&xb[j]);
        float4 ov;
        ov.x = xv.x + 0.75f * bf2f(hv.x) + hgs;
        ov.y = xv.y + 0.75f * bf2f(hv.y) + hgs;
        ov.z = xv.z + 0.75f * bf2f(hv.z) + hgs;
        ov.w = xv.w + 0.75f * bf2f(hv.w) + hgs;
        *reinterpret_cast<float4*>(&ob[j]) = ov;
    }
}

// ---------------- launch ----------------
extern "C" void kernel_launch(void* const* d_in, const int* in_sizes, int n_in,
                              void* d_out, int out_size, void* d_ws, size_t ws_size,
                              hipStream_t stream) {
    const float* x    = (const float*)d_in[0];
    const float* gnw  = (const float*)d_in[1];
    const float* gnb  = (const float*)d_in[2];
    const float* qw   = (const float*)d_in[3];
    const float* qb   = (const float*)d_in[4];
    const float* kw   = (const float*)d_in[5];
    const float* kb   = (const float*)d_in[6];
    const float* vw   = (const float*)d_in[7];
    const float* vb   = (const float*)d_in[8];
    const float* pjw  = (const float*)d_in[9];
    float* out = (float*)d_out;

    char* ws = (char*)d_ws;
    size_t off = 0;
    auto alloc = [&](size_t bytes) { void* p = ws + off; off += (bytes + 255) & ~(size_t)255; return p; };
    // qkv: contiguous [3][BB][27][HW] bf16 + 64B zero tail (k_hp_fused overread)
    __hip_bfloat16* qkvbuf = (__hip_bfloat16*)alloc((size_t)3 * BB * CHW * 2 + 64);
    __hip_bfloat16* qbf = qkvbuf;
    __hip_bfloat16* kbf = qkvbuf + (size_t)BB * CHW;
    __hip_bfloat16* vbf = qkvbuf + (size_t)2 * BB * CHW;
    // spart (37.9MB, dead after k_softmax) aliases gattn pacc (BB*GKS*GG*28 f32 = 19.7MB)
    float* spart = (float*)alloc((size_t)BB * NKS * NP * MPAD * 4);
    float* pacc  = spart;
    __hip_bfloat16* wHat = (__hip_bfloat16*)alloc((size_t)BB * WFRAG * 2);
    float* qg    = (float*)alloc((size_t)BB * GG * 27 * 4);
    float* kg    = (float*)alloc((size_t)BB * GG * 27 * 4);
    float* vg    = (float*)alloc((size_t)BB * GG * 27 * 4);
    float* hg    = (float*)alloc((size_t)BB * GG * 27 * 4);   // transposed [b][27][GG]
    float* part  = (float*)alloc((size_t)BB * 1024 * 2 * 4);
    float* stats = (float*)alloc((size_t)BB * 2 * 4);
    float* pvw   = (float*)alloc(729 * 4);
    float* pvb   = (float*)alloc(27 * 4);

    (void)hipMemsetAsync((char*)qkvbuf + (size_t)3 * BB * CHW * 2, 0, 64, stream);
    k_fold<<<1, 256, 0, stream>>>(pjw, vw, vb, pvw, pvb);
    k_gn_partial<<<BB * 1024, 256, 0, stream>>>(x, part);
    k_gn_final<<<BB, 256, 0, stream>>>(part, stats);
    k_qkv_mfma<<<(BB * HW) / 256, 256, 0, stream>>>(x, stats, qw, qb, kw, kb, pvw, pvb,
                                                    gnw, gnb, qkvbuf);
    k_pool<<<(BB * 27 * GG) / 256, 256, 0, stream>>>(qbf, qg);
    k_pool<<<(BB * 27 * GG) / 256, 256, 0, stream>>>(kbf, kg);
    k_pool<<<(BB * 27 * GG) / 256, 256, 0, stream>>>(vbf, vg);
    k_spart_mfma<<<BB * NKS, 448, 0, stream>>>(qbf, kbf, spart);
    k_softmax<<<BB * NP, 256, 0, stream>>>(spart, wHat);
    k_gattn_flash<<<BB * 49 * GKS, 256, 0, stream>>>(qg, kg, vg, pacc);
    k_gattn_reduce<<<(BB * GG * 27 + 255) / 256, 256, 0, stream>>>(pacc, hg);
    k_hp_fused<<<BB * 432, 256, 0, stream>>>(vbf, wHat, x, hg, out);
}

// Round 20
// 245.075 us; speedup vs baseline: 1.2234x; 1.0429x over previous
//
#include <hip/hip_runtime.h>
#include <hip/hip_bf16.h>
#include <cstdint>

// ---------------- problem constants ----------------
namespace {
constexpr int BB = 4;
constexpr int CC = 27;
constexpr int HW = 448 * 448;                 // 200704
constexpr long long CHW = (long long)CC * HW; // 5419008
constexpr int NP = 196;                        // patch positions
constexpr int GG = 56 * 56;                    // 3136 pooled positions
constexpr int DTOT = CC * 1024;                // 27648
constexpr float SCALE_P = 0.0060140449f;       // 1/sqrt(27648)
constexpr float SCALE_G = 0.1924500897f;       // 1/sqrt(27)
constexpr float EPSV = 1e-5f;
// MFMA spart config
constexpr int KCH = 512;                       // d-chunk per block
constexpr int NKS = DTOT / KCH;                // 54 partials
constexpr int MPAD = 224;                      // padded n/m (14 tiles of 16)
constexpr int ROWB = 128;                      // LDS bytes per row
// wHat fragment-major, step-major: [7 step][13 ct][64 lane][8 elem] bf16 = 46592 elems
constexpr int WFRAG = 7 * 13 * 64 * 8;
// qkv-MFMA config
constexpr int XST = 40;                        // LDS row stride (shorts)
constexpr int OST = 260;                       // output staging row stride (shorts)
// flash gattn config
constexpr int GKC = 224;                       // keys per chunk (14 chunks)
constexpr int GKS = 14;                        // key splits (1 chunk per block)
constexpr int KST = 40;                        // ks row stride (shorts)
constexpr int VST = 232;                       // vs/ps row stride (shorts)
// hp epilogue LDS stride (shorts, bf16)
constexpr int HST = 204;
}

typedef __attribute__((ext_vector_type(8))) short short8;
typedef __attribute__((ext_vector_type(4))) float f32x4;

__device__ __forceinline__ float bf2f(unsigned short u) {
    return __uint_as_float(((uint32_t)u) << 16);
}

__device__ __forceinline__ ushort f2bf(float f) {
    union { __hip_bfloat16 h; ushort u; } cv;
    cv.h = __float2bfloat16(f);
    return cv.u;
}

// ---------------- 0. fold proj into V weights: pvw = proj*vw, pvb = proj*vb ----------------
__global__ void k_fold(const float* __restrict__ pjw, const float* __restrict__ vw,
                       const float* __restrict__ vb, float* __restrict__ pvw,
                       float* __restrict__ pvb) {
    __shared__ float pj[729], vv[729], vbs[27];
    int t = threadIdx.x;
    for (int i = t; i < 729; i += 256) { pj[i] = pjw[i]; vv[i] = vw[i]; }
    if (t < 27) vbs[t] = vb[t];
    __syncthreads();
    for (int i = t; i < 729; i += 256) {
        int o = i / 27, c2 = i - (i / 27) * 27;
        float s = 0.f;
#pragma unroll
        for (int c = 0; c < 27; c++) s += pj[o * 27 + c] * vv[c * 27 + c2];
        pvw[i] = s;
    }
    if (t < 27) {
        float s = 0.f;
#pragma unroll
        for (int c = 0; c < 27; c++) s += pj[t * 27 + c] * vbs[c];
        pvb[t] = s;
    }
}

// ---------------- 1. GroupNorm stats ----------------
__global__ void k_gn_partial(const float* __restrict__ x, float* __restrict__ part) {
    int blk = blockIdx.x;          // BB*1024 blocks
    int b = blk >> 10;
    int chunk = blk & 1023;
    const int CLEN = (int)(CHW / 1024);   // 5292
    const float* p = x + (size_t)b * CHW + (size_t)chunk * CLEN;
    float s = 0.f, ss = 0.f;
    for (int i = threadIdx.x; i < CLEN; i += 256) {
        float v = p[i];
        s += v; ss += v * v;
    }
    for (int o = 32; o; o >>= 1) { s += __shfl_down(s, o); ss += __shfl_down(ss, o); }
    __shared__ float ls[4], lss[4];
    int wid = threadIdx.x >> 6, lane = threadIdx.x & 63;
    if (lane == 0) { ls[wid] = s; lss[wid] = ss; }
    __syncthreads();
    if (threadIdx.x == 0) {
        float S = ls[0] + ls[1] + ls[2] + ls[3];
        float SS = lss[0] + lss[1] + lss[2] + lss[3];
        part[blk * 2] = S; part[blk * 2 + 1] = SS;
    }
}

__global__ void k_gn_final(const float* __restrict__ part, float* __restrict__ stats) {
    int b = blockIdx.x;
    float s = 0.f, ss = 0.f;
    for (int i = threadIdx.x; i < 1024; i += 256) {
        s += part[(b * 1024 + i) * 2];
        ss += part[(b * 1024 + i) * 2 + 1];
    }
    for (int o = 32; o; o >>= 1) { s += __shfl_down(s, o); ss += __shfl_down(ss, o); }
    __shared__ float ls[4], lss[4];
    int wid = threadIdx.x >> 6, lane = threadIdx.x & 63;
    if (lane == 0) { ls[wid] = s; lss[wid] = ss; }
    __syncthreads();
    if (threadIdx.x == 0) {
        float S = ls[0] + ls[1] + ls[2] + ls[3];
        float SS = lss[0] + lss[1] + lss[2] + lss[3];
        float mean = S / (float)CHW;
        float var = SS / (float)CHW - mean * mean;
        stats[b * 2] = mean;
        stats[b * 2 + 1] = rsqrtf(var + EPSV);
    }
}

// ---------------- 2. GN-apply + QKV conv1x1 via MFMA (-> bf16) ----------------
// Output staged through LDS (aliasing xs, dead after MFMA) in 3 phases of 32
// channels -> each global store = 512B contiguous channel segment (ushort4/lane).
__global__ __launch_bounds__(256, 2)
void k_qkv_mfma(const float* __restrict__ x, const float* __restrict__ stats,
                const float* __restrict__ qw, const float* __restrict__ qb,
                const float* __restrict__ kw, const float* __restrict__ kb,
                const float* __restrict__ vw, const float* __restrict__ vb,
                const float* __restrict__ gnw, const float* __restrict__ gnb,
                __hip_bfloat16* __restrict__ qkv) {
    __shared__ ushort xs[256 * XST];            // 20480 B (aliased by osh later)
    __shared__ ushort wls[96 * XST];            // 7680 B
    __shared__ __align__(16) float bls[96];
    __shared__ float gwls[27], gbls[27];
    ushort* osh = xs;                           // 32 * OST = 8320 shorts <= 10240

    int tid = threadIdx.x;
    int P0 = blockIdx.x * 256;                  // global pixel base
    int b = P0 / HW;                            // HW % 256 == 0: no straddle
    int hw0 = P0 - b * HW;

    for (int i = tid; i < 96 * 32; i += 256) {
        int row = i >> 5, c = i & 31;
        float wv = 0.f;
        if (c < 27 && row < 81) {
            int t = (row >= 54) ? 2 : (row >= 27 ? 1 : 0);
            int oc = row - t * 27;
            const float* wp = (t == 0) ? qw : (t == 1) ? kw : vw;
            wv = wp[oc * 27 + c];
        }
        wls[row * XST + c] = f2bf(wv);
    }
    if (tid < 96) {
        float bv = 0.f;
        if (tid < 27) bv = qb[tid];
        else if (tid < 54) bv = kb[tid - 27];
        else if (tid < 81) bv = vb[tid - 54];
        bls[tid] = bv;
    }
    if (tid < 27) { gwls[tid] = gnw[tid]; gbls[tid] = gnb[tid]; }
    float mean = stats[b * 2], rstd = stats[b * 2 + 1];
    __syncthreads();

    {
        const float* xp = x + (size_t)b * CHW + hw0 + tid;
        ushort xv[28];
#pragma unroll
        for (int c = 0; c < 27; c++) {
            float v = (xp[(size_t)c * HW] - mean) * rstd * gwls[c] + gbls[c];
            xv[c] = f2bf(v);
        }
        xv[27] = 0;
        uint32_t* xrow = reinterpret_cast<uint32_t*>(&xs[tid * XST]);
#pragma unroll
        for (int i = 0; i < 14; i++)
            xrow[i] = (uint32_t)xv[2 * i] | ((uint32_t)xv[2 * i + 1] << 16);
        xrow[14] = 0; xrow[15] = 0;
    }
    __syncthreads();

    int w = tid >> 6, l = tid & 63;
    int lrow = l & 15, kg = l >> 4;

    short8 afr[6];
    f32x4 binit[6];
#pragma unroll
    for (int mt = 0; mt < 6; mt++) {
        afr[mt] = *reinterpret_cast<const short8*>(&wls[(mt * 16 + lrow) * XST + kg * 8]);
        binit[mt] = *reinterpret_cast<const f32x4*>(&bls[mt * 16 + kg * 4]);
    }

    f32x4 acc[4][6];
#pragma unroll
    for (int pt = 0; pt < 4; pt++) {
        const short8 bfr = *reinterpret_cast<const short8*>(
            &xs[(w * 64 + pt * 16 + lrow) * XST + kg * 8]);
#pragma unroll
        for (int mt = 0; mt < 6; mt++)
            acc[pt][mt] = __builtin_amdgcn_mfma_f32_16x16x32_bf16(afr[mt], bfr, binit[mt], 0, 0, 0);
    }

    // ---- 3-phase LDS-staged coalesced output ----
    ushort* ob = (ushort*)qkv;
#pragma unroll
    for (int p = 0; p < 3; p++) {
        __syncthreads();   // previous phase reads (or xs MFMA reads) done
        // stage channels o in [32p, 32p+32): mt = 2p, 2p+1
#pragma unroll
        for (int m2 = 0; m2 < 2; m2++) {
            int mt = 2 * p + m2;
            int rloc0 = m2 * 16 + kg * 4;          // local row base
#pragma unroll
            for (int pt = 0; pt < 4; pt++) {
                int px = w * 64 + pt * 16 + lrow;
#pragma unroll
                for (int r = 0; r < 4; r++)
                    osh[(rloc0 + r) * OST + px] = f2bf(acc[pt][mt][r]);
            }
        }
        __syncthreads();
        // store: wave w handles channels ch_local = 4k + w, k = 0..7
#pragma unroll
        for (int k = 0; k < 8; k++) {
            int ch = p * 32 + k * 4 + w;
            if (ch < 81) {
                int t = (ch >= 54) ? 2 : (ch >= 27 ? 1 : 0);
                int oc = ch - t * 27;
                const ushort4 val = *reinterpret_cast<const ushort4*>(
                    &osh[(k * 4 + w) * OST + l * 4]);
                *reinterpret_cast<ushort4*>(
                    &ob[((size_t)t * BB + b) * CHW + (size_t)oc * HW + hw0 + l * 4]) = val;
            }
        }
    }
}

// ---------------- 3. fused 8x8 avg pool (q,k,v) -> transposed [t][b][g][27] ----------------
__global__ void k_pool3(const __hip_bfloat16* __restrict__ qkv, float* __restrict__ dst) {
    int idx = blockIdx.x * 256 + threadIdx.x;  // < 3*4*27*3136 = 1016064
    int tsr = idx / (BB * 27 * GG);            // tensor 0..2
    int rem = idx - tsr * (BB * 27 * GG);
    int g = rem % GG;
    int t = rem / GG;
    int c = t % 27;
    int b = t / 27;
    int gh = g / 56, gw = g - (g / 56) * 56;
    const ushort* sp = (const ushort*)qkv + (size_t)tsr * BB * CHW +
                       (size_t)(b * 27 + c) * HW + (size_t)(gh * 8) * 448 + gw * 8;
    float s = 0.f;
#pragma unroll
    for (int r = 0; r < 8; r++) {
        const ushort4 a = *reinterpret_cast<const ushort4*>(sp + r * 448);
        const ushort4 d = *reinterpret_cast<const ushort4*>(sp + r * 448 + 4);
        s += bf2f(a.x) + bf2f(a.y) + bf2f(a.z) + bf2f(a.w)
           + bf2f(d.x) + bf2f(d.y) + bf2f(d.z) + bf2f(d.w);
    }
    dst[(size_t)tsr * BB * GG * 27 + ((size_t)b * GG + g) * 27 + c] = s * (1.f / 64.f);
}

// ---------------- 4a. patch attention S partials via MFMA ----------------
__global__ __launch_bounds__(448, 1)
void k_spart_mfma(const __hip_bfloat16* __restrict__ q, const __hip_bfloat16* __restrict__ k,
                  float* __restrict__ spart) {
    __shared__ ushort lq[MPAD * 64];   // 28672 B
    __shared__ ushort lk[MPAD * 64];
    int blk = blockIdx.x;              // 4b * 54ks = 216
    int ks = blk % NKS;
    int b = blk / NKS;
    const ushort* qb_ = (const ushort*)q + (size_t)b * CHW;
    const ushort* kb_ = (const ushort*)k + (size_t)b * CHW;
    int t = threadIdx.x;
    int w = t >> 6, l = t & 63;
    int lrow = l & 15, lg = l >> 4;    // fragment coords
    int sr = t & 15;                   // d-pair index 0..15 (d = 2sr, 2sr+1)
    int sn8 = t >> 4;                  // col-chunk 0..27 (cols sn8*8..+8)

    f32x4 acc[2][13];
#pragma unroll
    for (int i = 0; i < 2; i++)
#pragma unroll
        for (int ct = 0; ct < 13; ct++) acc[i][ct] = (f32x4){0.f, 0.f, 0.f, 0.f};

    int d0 = ks * KCH;
    for (int step = 0; step < KCH / 32; ++step) {
        int dbase = d0 + step * 32;
        {
            const ushort* s0 = qb_ + (size_t)(dbase + 2 * sr) * NP + sn8 * 8;
            const ushort* s1 = s0 + NP;
            ushort4 a0 = *reinterpret_cast<const ushort4*>(s0);
            ushort4 a1 = *reinterpret_cast<const ushort4*>(s0 + 4);
            ushort4 b0 = *reinterpret_cast<const ushort4*>(s1);
            ushort4 b1 = *reinterpret_cast<const ushort4*>(s1 + 4);
            ushort ra[8] = {a0.x, a0.y, a0.z, a0.w, a1.x, a1.y, a1.z, a1.w};
            ushort rb[8] = {b0.x, b0.y, b0.z, b0.w, b1.x, b1.y, b1.z, b1.w};
#pragma unroll
            for (int kk = 0; kk < 8; kk++) {
                int n = sn8 * 8 + kk;
                uint32_t val = (uint32_t)ra[kk] | ((uint32_t)rb[kk] << 16);
                *reinterpret_cast<uint32_t*>(reinterpret_cast<char*>(lq) + n * ROWB +
                                             ((4 * sr) ^ (16 * (n & 7)))) = val;
            }
        }
        {
            const ushort* s0 = kb_ + (size_t)(dbase + 2 * sr) * NP + sn8 * 8;
            const ushort* s1 = s0 + NP;
            ushort4 a0 = *reinterpret_cast<const ushort4*>(s0);
            ushort4 a1 = *reinterpret_cast<const ushort4*>(s0 + 4);
            ushort4 b0 = *reinterpret_cast<const ushort4*>(s1);
            ushort4 b1 = *reinterpret_cast<const ushort4*>(s1 + 4);
            ushort ra[8] = {a0.x, a0.y, a0.z, a0.w, a1.x, a1.y, a1.z, a1.w};
            ushort rb[8] = {b0.x, b0.y, b0.z, b0.w, b1.x, b1.y, b1.z, b1.w};
#pragma unroll
            for (int kk = 0; kk < 8; kk++) {
                int m = sn8 * 8 + kk;
                uint32_t val = (uint32_t)ra[kk] | ((uint32_t)rb[kk] << 16);
                *reinterpret_cast<uint32_t*>(reinterpret_cast<char*>(lk) + m * ROWB +
                                             ((4 * sr) ^ (16 * (m & 7)))) = val;
            }
        }
        __syncthreads();
        int nA0 = (2 * w) * 16 + lrow;
        int nA1 = nA0 + 16;
        const short8 afr0 = *reinterpret_cast<const short8*>(
            reinterpret_cast<const char*>(lq) + nA0 * ROWB + 16 * (lg ^ (nA0 & 7)));
        const short8 afr1 = *reinterpret_cast<const short8*>(
            reinterpret_cast<const char*>(lq) + nA1 * ROWB + 16 * (lg ^ (nA1 & 7)));
#pragma unroll
        for (int ct = 0; ct < 13; ct++) {
            int m = ct * 16 + lrow;
            const short8 bfr = *reinterpret_cast<const short8*>(
                reinterpret_cast<const char*>(lk) + m * ROWB + 16 * (lg ^ (m & 7)));
            acc[0][ct] = __builtin_amdgcn_mfma_f32_16x16x32_bf16(afr0, bfr, acc[0][ct], 0, 0, 0);
            acc[1][ct] = __builtin_amdgcn_mfma_f32_16x16x32_bf16(afr1, bfr, acc[1][ct], 0, 0, 0);
        }
        __syncthreads();
    }
    float* sp = spart + (size_t)(b * NKS + ks) * NP * MPAD;
#pragma unroll
    for (int i = 0; i < 2; i++) {
        int rt = 2 * w + i;
#pragma unroll
        for (int r = 0; r < 4; r++) {
            int n = rt * 16 + lg * 4 + r;
            if (n < NP) {
#pragma unroll
                for (int ct = 0; ct < 13; ct++)
                    sp[(size_t)n * MPAD + ct * 16 + lrow] = acc[i][ct][r];
            }
        }
    }
}

// ---------------- 4b. reduce + row softmax -> whf fragment-major (step-major) bf16 ----------------
__global__ void k_softmax(const float* __restrict__ spart, __hip_bfloat16* __restrict__ whf) {
    int blk = blockIdx.x;        // BB*196
    int n = blk % NP;            // query row
    int b = blk / NP;
    int m = threadIdx.x;         // key col
    float val = -1e30f;
    if (m < 196) {
        float s = 0.f;
        for (int ks = 0; ks < NKS; ks++)
            s += spart[((size_t)(b * NKS + ks) * NP + n) * MPAD + m];
        val = s * SCALE_P;
    }
    float mx = val;
    for (int o = 32; o; o >>= 1) mx = fmaxf(mx, __shfl_xor(mx, o));
    __shared__ float redm[4], reds[4];
    int wid = threadIdx.x >> 6, lane = threadIdx.x & 63;
    if (lane == 0) redm[wid] = mx;
    __syncthreads();
    mx = fmaxf(fmaxf(redm[0], redm[1]), fmaxf(redm[2], redm[3]));
    float p = (m < 196) ? __expf(val - mx) : 0.f;
    float sm = p;
    for (int o = 32; o; o >>= 1) sm += __shfl_xor(sm, o);
    if (lane == 0) reds[wid] = sm;
    __syncthreads();
    sm = reds[0] + reds[1] + reds[2] + reds[3];
    if (m < 224) {
        int ct = n >> 4, lr = n & 15;
        int step = m >> 5, kg = (m >> 3) & 3, e = m & 7;
        size_t addr = (size_t)b * WFRAG +
                      (((size_t)(step * 13 + ct) * 64 + kg * 16 + lr) << 3) + e;
        whf[addr] = __float2bfloat16((m < 196) ? p / sm : 0.f);
    }
}

// ---------------- 5a. global pooled attention: split-K flash MFMA partials ----------------
__global__ __launch_bounds__(256)
void k_gattn_flash(const float* __restrict__ qg, const float* __restrict__ kg,
                   const float* __restrict__ vg, float* __restrict__ pacc) {
    __shared__ __align__(16) ushort ksh[GKC * KST];    // [k][d] 17920 B
    __shared__ __align__(16) ushort vsh[32 * VST];     // [d][k] 14848 B
    __shared__ __align__(16) ushort psh[4][16 * VST];  // per-wave P [q][k] 29696 B

    int blk = blockIdx.x;              // BB * 49 * GKS = 2744
    int ks = blk % GKS;
    int t2 = blk / GKS;
    int b = t2 / 49;
    int q0 = (t2 % 49) * 64;
    int tid = threadIdx.x;
    int w = tid >> 6, l = tid & 63;
    int lr = l & 15, lg = l >> 4;

    for (int i = tid; i < GKC; i += 256) {
        ushort* kr = &ksh[i * KST];
        kr[27] = 0; kr[28] = 0; kr[29] = 0; kr[30] = 0; kr[31] = 0;
        vsh[27 * VST + i] = 0x3f80;    // bf16 1.0
        vsh[28 * VST + i] = 0; vsh[29 * VST + i] = 0;
        vsh[30 * VST + i] = 0; vsh[31 * VST + i] = 0;
    }

    short8 aq;
    {
        const float* qr = qg + ((size_t)b * GG + q0 + w * 16 + lr) * 27;
#pragma unroll
        for (int j = 0; j < 8; j++) {
            int c = 8 * lg + j;
            aq[j] = (c < 27) ? (short)f2bf(qr[c]) : (short)0;
        }
    }

    f32x4 acc_h0 = {0.f, 0.f, 0.f, 0.f};
    f32x4 acc_h1 = {0.f, 0.f, 0.f, 0.f};
    ushort* myps = &psh[w][0];
    const float* kgb = kg + (size_t)b * GG * 27;
    const float* vgb = vg + (size_t)b * GG * 27;

    {
        int ch = ks;
        int base = ch * GKC * 27;
        for (int idx = tid; idx < GKC * 27; idx += 256) {
            int kk = idx / 27, c = idx - (idx / 27) * 27;
            ksh[kk * KST + c] = f2bf(kgb[base + idx]);
            vsh[c * VST + kk] = f2bf(vgb[base + idx]);
        }
        __syncthreads();

        f32x4 s[14];
#pragma unroll
        for (int ct = 0; ct < 14; ct++) {
            const short8 bk = *reinterpret_cast<const short8*>(
                &ksh[(ct * 16 + lr) * KST + 8 * lg]);
            s[ct] = __builtin_amdgcn_mfma_f32_16x16x32_bf16(
                aq, bk, (f32x4){0.f, 0.f, 0.f, 0.f}, 0, 0, 0);
        }
#pragma unroll
        for (int ct = 0; ct < 14; ct++) {
#pragma unroll
            for (int r = 0; r < 4; r++) {
                float p = __expf(s[ct][r] * SCALE_G);
                myps[(4 * lg + r) * VST + ct * 16 + lr] = f2bf(p);
            }
        }
#pragma unroll
        for (int kstep = 0; kstep < 7; kstep++) {
            const short8 ap = *reinterpret_cast<const short8*>(
                &myps[lr * VST + kstep * 32 + 8 * lg]);
            const short8 bv0 = *reinterpret_cast<const short8*>(
                &vsh[lr * VST + kstep * 32 + 8 * lg]);
            const short8 bv1 = *reinterpret_cast<const short8*>(
                &vsh[(16 + lr) * VST + kstep * 32 + 8 * lg]);
            acc_h0 = __builtin_amdgcn_mfma_f32_16x16x32_bf16(ap, bv0, acc_h0, 0, 0, 0);
            acc_h1 = __builtin_amdgcn_mfma_f32_16x16x32_bf16(ap, bv1, acc_h1, 0, 0, 0);
        }
    }

    // epilogue: unnormalized partials; d=27 (in acc_h1 col 11) is l
#pragma unroll
    for (int r = 0; r < 4; r++) {
        int q = q0 + w * 16 + 4 * lg + r;
        float* pr = pacc + (((size_t)(b * GKS + ks) * GG + q) * 28);
        pr[lr] = acc_h0[r];
        if (lr < 12) pr[16 + lr] = acc_h1[r];   // d=16..27 incl. l
    }
}

// ---------------- 5b. combine split-K partials -> hg TRANSPOSED [b][27][GG] ----------------
__global__ void k_gattn_reduce(const float* __restrict__ pacc, float* __restrict__ hg) {
    int t = blockIdx.x * 256 + threadIdx.x;   // < BB*GG*27 = 338688
    if (t >= BB * GG * 27) return;
    int c = t % 27;
    int g = (t / 27) % GG;
    int b = t / (27 * GG);
    float a = 0.f, lsum = 0.f;
#pragma unroll
    for (int ks = 0; ks < GKS; ks++) {
        const float* pr = pacc + (((size_t)(b * GKS + ks) * GG + g) * 28);
        a += pr[c];
        lsum += pr[27];
    }
    hg[((size_t)b * 27 + c) * GG + g] = a / lsum;
}

// ---------------- 6. h_patch GEMM via MFMA + bf16-LDS coalesced epilogue ----------------
__global__ __launch_bounds__(256)
void k_hp_fused(const __hip_bfloat16* __restrict__ v, const __hip_bfloat16* __restrict__ whf,
                const float* __restrict__ x, const float* __restrict__ hg,
                float* __restrict__ out) {
    __shared__ __align__(16) ushort hbuf[64 * HST];   // 26112 B
    int nper = gridDim.x >> 3;         // 216
    int bid = blockIdx.x;
    int blk = (bid & 7) * nper + (bid >> 3);   // bijective XCD swizzle
    int b = blk / 432;
    int grp = blk % 432;
    int tid = threadIdx.x;
    int w = tid >> 6, l = tid & 63;
    int ar = l & 15;                   // A row within tile / B col
    int kg = l >> 4;                   // k-group
    int D0 = (grp * 4 + w) * 16;       // d-tile base

    // ---- early x prefetch (epilogue operand) ----
    int c = grp >> 4;                      // (grp*64) >> 10
    int pix0 = (grp & 15) * 64 * NP;       // strip_base * 196
    const float* xb = x + (size_t)b * CHW + (size_t)c * HW + pix0;
    float4 xpre[12];
#pragma unroll
    for (int it = 0; it < 12; ++it)
        xpre[it] = *reinterpret_cast<const float4*>(&xb[(tid + it * 256) * 4]);
    __builtin_amdgcn_sched_barrier(0);     // pin load issue here (waitcnt stays at use)

    const ushort* vb = (const ushort*)v + (size_t)b * CHW;
    const ushort* wf = (const ushort*)whf + (size_t)b * WFRAG;

    const ushort* arow = vb + (size_t)(D0 + ar) * NP;
    short8 av[7];
#pragma unroll
    for (int step = 0; step < 7; ++step) {
        int joff = step * 32 + kg * 8;
        ushort4 alo = *reinterpret_cast<const ushort4*>(arow + joff);
        ushort4 ahi = *reinterpret_cast<const ushort4*>(arow + joff + 4);
        av[step][0] = alo.x; av[step][1] = alo.y; av[step][2] = alo.z; av[step][3] = alo.w;
        av[step][4] = ahi.x; av[step][5] = ahi.y; av[step][6] = ahi.z; av[step][7] = ahi.w;
    }

    f32x4 acc[13];
#pragma unroll
    for (int ct = 0; ct < 13; ct++) acc[ct] = (f32x4){0.f, 0.f, 0.f, 0.f};

#pragma unroll
    for (int step = 0; step < 7; ++step) {
        short8 bv[13];
#pragma unroll
        for (int ct = 0; ct < 13; ct++)
            bv[ct] = *reinterpret_cast<const short8*>(
                wf + (((size_t)(step * 13 + ct) * 64 + l) << 3));
#pragma unroll
        for (int ct = 0; ct < 13; ct++)
            acc[ct] = __builtin_amdgcn_mfma_f32_16x16x32_bf16(av[step], bv[ct], acc[ct], 0, 0, 0);
    }

#pragma unroll
    for (int ct = 0; ct < 13; ct++) {
        int i = ct * 16 + ar;
        if (i < NP) {
#pragma unroll
            for (int r = 0; r < 4; r++)
                hbuf[(w * 16 + kg * 4 + r) * HST + i] = f2bf(acc[ct][r]);
        }
    }
    __syncthreads();

    float* ob = out + (size_t)b * CHW + (size_t)c * HW + pix0;
    const float* hgc = hg + ((size_t)b * 27 + c) * GG;   // transposed row for channel c
#pragma unroll
    for (int it = 0; it < 12; ++it) {
        int idx4 = tid + it * 256;
        int j = idx4 * 4;
        int sl = j / NP;
        int i = j - sl * NP;
        ushort4 hv = *reinterpret_cast<const ushort4*>(&hbuf[sl * HST + i]);
        int pix = pix0 + j;
        int h = pix / 448;
        int w2 = pix - h * 448;
        int g = (h >> 3) * 56 + (w2 >> 3);
        float hgs = 0.25f * hgc[g];
        float4 xv = xpre[it];
        float4 ov;
        ov.x = xv.x + 0.75f * bf2f(hv.x) + hgs;
        ov.y = xv.y + 0.75f * bf2f(hv.y) + hgs;
        ov.z = xv.z + 0.75f * bf2f(hv.z) + hgs;
        ov.w = xv.w + 0.75f * bf2f(hv.w) + hgs;
        *reinterpret_cast<float4*>(&ob[j]) = ov;
    }
    if (tid < 64) {
        int idx4 = 3072 + tid;
        int j = idx4 * 4;
        int sl = j / NP;
        int i = j - sl * NP;
        ushort4 hv = *reinterpret_cast<const ushort4*>(&hbuf[sl * HST + i]);
        int pix = pix0 + j;
        int h = pix / 448;
        int w2 = pix - h * 448;
        int g = (h >> 3) * 56 + (w2 >> 3);
        float hgs = 0.25f * hgc[g];
        float4 xv = *reinterpret_cast<const float4*>(&xb[j]);
        float4 ov;
        ov.x = xv.x + 0.75f * bf2f(hv.x) + hgs;
        ov.y = xv.y + 0.75f * bf2f(hv.y) + hgs;
        ov.z = xv.z + 0.75f * bf2f(hv.z) + hgs;
        ov.w = xv.w + 0.75f * bf2f(hv.w) + hgs;
        *reinterpret_cast<float4*>(&ob[j]) = ov;
    }
}

// ---------------- launch ----------------
extern "C" void kernel_launch(void* const* d_in, const int* in_sizes, int n_in,
                              void* d_out, int out_size, void* d_ws, size_t ws_size,
                              hipStream_t stream) {
    const float* x    = (const float*)d_in[0];
    const float* gnw  = (const float*)d_in[1];
    const float* gnb  = (const float*)d_in[2];
    const float* qw   = (const float*)d_in[3];
    const float* qb   = (const float*)d_in[4];
    const float* kw   = (const float*)d_in[5];
    const float* kb   = (const float*)d_in[6];
    const float* vw   = (const float*)d_in[7];
    const float* vb   = (const float*)d_in[8];
    const float* pjw  = (const float*)d_in[9];
    float* out = (float*)d_out;

    char* ws = (char*)d_ws;
    size_t off = 0;
    auto alloc = [&](size_t bytes) { void* p = ws + off; off += (bytes + 255) & ~(size_t)255; return p; };
    // qkv: contiguous [3][BB][27][HW] bf16 + 64B zero tail (k_hp_fused overread)
    __hip_bfloat16* qkvbuf = (__hip_bfloat16*)alloc((size_t)3 * BB * CHW * 2 + 64);
    __hip_bfloat16* qbf = qkvbuf;
    __hip_bfloat16* kbf = qkvbuf + (size_t)BB * CHW;
    __hip_bfloat16* vbf = qkvbuf + (size_t)2 * BB * CHW;
    // spart (37.9MB, dead after k_softmax) aliases gattn pacc (BB*GKS*GG*28 f32 = 19.7MB)
    float* spart = (float*)alloc((size_t)BB * NKS * NP * MPAD * 4);
    float* pacc  = spart;
    __hip_bfloat16* wHat = (__hip_bfloat16*)alloc((size_t)BB * WFRAG * 2);
    // qg,kg,vg contiguous (each BB*GG*27*4 = 1354752 B, 256-aligned)
    float* qg    = (float*)alloc((size_t)3 * BB * GG * 27 * 4);
    float* kg    = qg + (size_t)BB * GG * 27;
    float* vg    = qg + (size_t)2 * BB * GG * 27;
    float* hg    = (float*)alloc((size_t)BB * GG * 27 * 4);   // transposed [b][27][GG]
    float* part  = (float*)alloc((size_t)BB * 1024 * 2 * 4);
    float* stats = (float*)alloc((size_t)BB * 2 * 4);
    float* pvw   = (float*)alloc(729 * 4);
    float* pvb   = (float*)alloc(27 * 4);

    (void)hipMemsetAsync((char*)qkvbuf + (size_t)3 * BB * CHW * 2, 0, 64, stream);
    k_fold<<<1, 256, 0, stream>>>(pjw, vw, vb, pvw, pvb);
    k_gn_partial<<<BB * 1024, 256, 0, stream>>>(x, part);
    k_gn_final<<<BB, 256, 0, stream>>>(part, stats);
    k_qkv_mfma<<<(BB * HW) / 256, 256, 0, stream>>>(x, stats, qw, qb, kw, kb, pvw, pvb,
                                                    gnw, gnb, qkvbuf);
    k_pool3<<<(3 * BB * 27 * GG) / 256, 256, 0, stream>>>(qkvbuf, qg);
    k_spart_mfma<<<BB * NKS, 448, 0, stream>>>(qbf, kbf, spart);
    k_softmax<<<BB * NP, 256, 0, stream>>>(spart, wHat);
    k_gattn_flash<<<BB * 49 * GKS, 256, 0, stream>>>(qg, kg, vg, pacc);
    k_gattn_reduce<<<(BB * GG * 27 + 255) / 256, 256, 0, stream>>>(pacc, hg);
    k_hp_fused<<<BB * 432, 256, 0, stream>>>(vbf, wHat, x, hg, out);
}